// Round 1
// baseline (511.817 us; speedup 1.0000x reference)
//
#include <hip/hip_runtime.h>

typedef _Float16 f16;
typedef _Float16 half8 __attribute__((ext_vector_type(8)));
typedef _Float16 half4 __attribute__((ext_vector_type(4)));
typedef float    f32x4 __attribute__((ext_vector_type(4)));

#define DEV static __device__ __forceinline__

constexpr int NB = 8, CH = 512, HW = 4096, IH = 64, IW = 64;
constexpr int BM = 64, BN = 64, BK = 64;
constexpr int LDT = BK + 8;   // LDS pitch in halves (144 B: 16B-aligned, 2-way-free banks)

// ---------------- staging helpers (256 threads) ----------------
// f16 global [rows][ld] -> LDS [64][LDT]
DEV void stage_f16(f16* dst, const f16* src, int ld) {
  const int t = threadIdx.x;
#pragma unroll
  for (int q0 = 0; q0 < 2; ++q0) {
    const int q = t + q0 * 256;              // 512 chunks of 8 halves
    const int r = q >> 3, cc = q & 7;
    *(half8*)(dst + r * LDT + cc * 8) = *(const half8*)(src + (long)r * ld + cc * 8);
  }
}

// fp32 global [rows][ld] -> hi/lo f16 LDS tiles
DEV void stage_f32_split(f16* dh, f16* dl, const float* src, int ld) {
  const int t = threadIdx.x;
#pragma unroll
  for (int q0 = 0; q0 < 4; ++q0) {
    const int q = t + q0 * 256;              // 1024 chunks of 4 floats
    const int r = q >> 4, cc = q & 15;
    f32x4 v = *(const f32x4*)(src + (long)r * ld + cc * 4);
    half4 h, l;
#pragma unroll
    for (int i = 0; i < 4; ++i) {
      f16 hi = (f16)v[i];
      h[i] = hi;
      l[i] = (f16)(v[i] - (float)hi);
    }
    *(half4*)(dh + r * LDT + cc * 4) = h;
    *(half4*)(dl + r * LDT + cc * 4) = l;
  }
}

// fp32 global [chan][ld] -> TRANSPOSED f16 LDS [pixel][chan] (hi only); 4x4 reg transpose
DEV void stage_f32_T(f16* dst, const float* src, int ld) {
  const int t = threadIdx.x;
  const int pb = t & 15, kb = t >> 4;        // pixels 4*pb.., chans 4*kb..
  f16 m[4][4];
#pragma unroll
  for (int j = 0; j < 4; ++j) {
    f32x4 v = *(const f32x4*)(src + (long)(kb * 4 + j) * ld + pb * 4);
#pragma unroll
    for (int i = 0; i < 4; ++i) m[i][j] = (f16)v[i];
  }
#pragma unroll
  for (int i = 0; i < 4; ++i) {
    half4 w;
#pragma unroll
    for (int j = 0; j < 4; ++j) w[j] = m[i][j];
    *(half4*)(dst + (pb * 4 + i) * LDT + kb * 4) = w;
  }
}

// ---------------- generic MFMA GEMM ----------------
// Computes O = A(MxK) * B(KxN) (+epilogue). Both operands staged as [outdim][k] row-major
// tiles; frag layout: A row = lane&15, k = (lane>>4)*8+i ; B col = lane&15 same k.
// C/D: col = lane&15, row = (lane>>4)*4 + reg  [verified mapping, learn_hip m89/m91].
// ASRC: 0 = f16 ptrs (Ah[,Al]); 1 = fp32, convert+split during staging.
// BSRC: 0 = f16 ptrs; 1 = fp32 split; 2 = fp32 transpose (hi only).
// SPLIT: 3-term hi/lo MFMA (AhBh + AhBl + AlBh).
// EPI: 0 = write split f16 (O1=hi,O2=lo); 1 = fp32 + rank1 (scores);
//      2 = f16 single; 3 = out = x + 0.1*(acc + ab3)   (denoised+residual)
template <int ASRC, int BSRC, bool SPLIT, int EPI>
__global__ __launch_bounds__(256) void gemm_k(
    const void* __restrict__ Ap, const void* __restrict__ A2p, long sAb, int lda,
    const void* __restrict__ Bp, const void* __restrict__ B2p, long sBb, int ldb,
    void* __restrict__ O1, void* __restrict__ O2, long sOb, int ldo, int K,
    const float* __restrict__ e0, const float* __restrict__ e1,
    const float* __restrict__ e2, const float* __restrict__ e3) {
  __shared__ f16 sAh[BM * LDT];
  __shared__ f16 sBh[BN * LDT];
  __shared__ f16 sAl[SPLIT ? BM * LDT : 1];
  __shared__ f16 sBl[SPLIT ? BN * LDT : 1];

  const int b = blockIdx.z;
  const int m0 = blockIdx.x * BM, n0 = blockIdx.y * BN;
  const int lane = threadIdx.x & 63, wave = threadIdx.x >> 6;
  const int wr = (wave >> 1) * 32, wc = (wave & 1) * 32;
  const int fr = lane & 15, fq = lane >> 4;

  f32x4 acc[2][2] = {};

  for (int k0 = 0; k0 < K; k0 += BK) {
    if constexpr (ASRC == 0) {
      stage_f16(sAh, (const f16*)Ap + b * sAb + (long)m0 * lda + k0, lda);
      if constexpr (SPLIT)
        stage_f16(sAl, (const f16*)A2p + b * sAb + (long)m0 * lda + k0, lda);
    } else {
      stage_f32_split(sAh, sAl, (const float*)Ap + b * sAb + (long)m0 * lda + k0, lda);
    }
    if constexpr (BSRC == 0) {
      stage_f16(sBh, (const f16*)Bp + b * sBb + (long)n0 * ldb + k0, ldb);
      if constexpr (SPLIT)
        stage_f16(sBl, (const f16*)B2p + b * sBb + (long)n0 * ldb + k0, ldb);
    } else if constexpr (BSRC == 1) {
      stage_f32_split(sBh, sBl, (const float*)Bp + b * sBb + (long)n0 * ldb + k0, ldb);
    } else {
      stage_f32_T(sBh, (const float*)Bp + b * sBb + (long)k0 * ldb + n0, ldb);
    }
    __syncthreads();
#pragma unroll
    for (int kk = 0; kk < 2; ++kk) {
      half8 ah[2], bh[2];
#pragma unroll
      for (int mi = 0; mi < 2; ++mi)
        ah[mi] = *(const half8*)&sAh[(wr + mi * 16 + fr) * LDT + kk * 32 + fq * 8];
#pragma unroll
      for (int ni = 0; ni < 2; ++ni)
        bh[ni] = *(const half8*)&sBh[(wc + ni * 16 + fr) * LDT + kk * 32 + fq * 8];
      if constexpr (SPLIT) {
        half8 al[2], bl[2];
#pragma unroll
        for (int mi = 0; mi < 2; ++mi)
          al[mi] = *(const half8*)&sAl[(wr + mi * 16 + fr) * LDT + kk * 32 + fq * 8];
#pragma unroll
        for (int ni = 0; ni < 2; ++ni)
          bl[ni] = *(const half8*)&sBl[(wc + ni * 16 + fr) * LDT + kk * 32 + fq * 8];
#pragma unroll
        for (int mi = 0; mi < 2; ++mi)
#pragma unroll
          for (int ni = 0; ni < 2; ++ni) {
            acc[mi][ni] = __builtin_amdgcn_mfma_f32_16x16x32_f16(ah[mi], bh[ni], acc[mi][ni], 0, 0, 0);
            acc[mi][ni] = __builtin_amdgcn_mfma_f32_16x16x32_f16(ah[mi], bl[ni], acc[mi][ni], 0, 0, 0);
            acc[mi][ni] = __builtin_amdgcn_mfma_f32_16x16x32_f16(al[mi], bh[ni], acc[mi][ni], 0, 0, 0);
          }
      } else {
#pragma unroll
        for (int mi = 0; mi < 2; ++mi)
#pragma unroll
          for (int ni = 0; ni < 2; ++ni)
            acc[mi][ni] = __builtin_amdgcn_mfma_f32_16x16x32_f16(ah[mi], bh[ni], acc[mi][ni], 0, 0, 0);
      }
    }
    __syncthreads();
  }

#pragma unroll
  for (int mi = 0; mi < 2; ++mi)
#pragma unroll
    for (int ni = 0; ni < 2; ++ni)
#pragma unroll
      for (int j = 0; j < 4; ++j) {
        const int row = m0 + wr + mi * 16 + fq * 4 + j;
        const int col = n0 + wc + ni * 16 + fr;
        float g = acc[mi][ni][j];
        if constexpr (EPI == 0) {
          f16 h = (f16)g;
          ((f16*)O1)[b * sOb + (long)row * ldo + col] = h;
          ((f16*)O2)[b * sOb + (long)row * ldo + col] = (f16)(g - (float)h);
        } else if constexpr (EPI == 1) {
          g += e0[row] * e1[b * CH + col] + e2[b * CH + row] * e3[col];
          ((float*)O1)[b * sOb + (long)row * ldo + col] = g;
        } else if constexpr (EPI == 2) {
          ((f16*)O1)[b * sOb + (long)row * ldo + col] = (f16)g;
        } else {
          const float xv = e0[((long)b * CH + row) * HW + col];
          ((float*)O1)[b * sOb + (long)row * ldo + col] = xv + 0.1f * (g + e1[b * CH + row]);
        }
      }
}

// ---------------- reductions ----------------
template <int OP>  // 0 = sum, 1 = max
DEV float blockReduce(float v) {
#pragma unroll
  for (int o = 32; o; o >>= 1) {
    float w = __shfl_xor(v, o);
    v = OP ? fmaxf(v, w) : v + w;
  }
  __shared__ float t[4];
  __shared__ float res;
  __syncthreads();
  if ((threadIdx.x & 63) == 0) t[threadIdx.x >> 6] = v;
  __syncthreads();
  if (threadIdx.x == 0)
    res = OP ? fmaxf(fmaxf(t[0], t[1]), fmaxf(t[2], t[3])) : t[0] + t[1] + t[2] + t[3];
  __syncthreads();
  return res;
}

// ---------------- small kernels ----------------
__global__ __launch_bounds__(256) void prep_w(const float* __restrict__ w1, const float* __restrict__ w2,
                                              const float* __restrict__ w3, f16* w1h, f16* w1l, f16* w2h,
                                              f16* w2l, f16* w3t) {
  const int i = blockIdx.x * 256 + threadIdx.x;
  if (i >= CH * CH) return;
  float a = w1[i];
  f16 h = (f16)a;
  w1h[i] = h;
  w1l[i] = (f16)(a - (float)h);
  float b = w2[i];
  h = (f16)b;
  w2h[i] = h;
  w2l[i] = (f16)(b - (float)h);
  const int r = i >> 9, c = i & 511;      // w3[r][c] -> w3t[c][r]
  w3t[c * CH + r] = (f16)w3[i];
}

__global__ __launch_bounds__(256) void rowsum_k(const float* __restrict__ x, float* __restrict__ s) {
  const int b = blockIdx.y, c = blockIdx.x;
  const float* p = x + ((long)(b * CH + c)) * HW;
  float a = 0.f;
  for (int i = threadIdx.x; i < HW; i += 256) a += p[i];
  a = blockReduce<0>(a);
  if (threadIdx.x == 0) s[b * CH + c] = a;
}

__global__ __launch_bounds__(256) void prep_tu(const float* __restrict__ w1, const float* __restrict__ w2,
                                               const float* __restrict__ b2, const float* __restrict__ s,
                                               float* __restrict__ t, float* __restrict__ u) {
  const int b = blockIdx.y, c = blockIdx.x;
  float a1 = 0.f, a2 = 0.f;
  for (int i = threadIdx.x; i < CH; i += 256) {
    float sv = s[b * CH + i];
    a1 += w1[(long)c * CH + i] * sv;
    a2 += w2[(long)c * CH + i] * sv;
  }
  a1 = blockReduce<0>(a1);
  a2 = blockReduce<0>(a2);
  if (threadIdx.x == 0) {
    t[b * CH + c] = a1;
    u[b * CH + c] = a2 + (float)HW * b2[c];
  }
}

__global__ __launch_bounds__(256) void softmax_k(const float* __restrict__ sc, const float* __restrict__ b3,
                                                 f16* __restrict__ attn, float* __restrict__ ab3) {
  const int b = blockIdx.y, c = blockIdx.x;
  const float* row = sc + ((long)(b * CH + c)) * CH;
  const float v0 = row[threadIdx.x], v1 = row[threadIdx.x + 256];
  const float m = blockReduce<1>(fmaxf(v0, v1));
  const float q0 = __expf(v0 - m), q1 = __expf(v1 - m);
  const float sum = blockReduce<0>(q0 + q1);
  const float sb = blockReduce<0>(q0 * b3[threadIdx.x] + q1 * b3[threadIdx.x + 256]);
  const float inv = 1.f / sum;
  attn[((long)(b * CH + c)) * CH + threadIdx.x] = (f16)(q0 * inv);
  attn[((long)(b * CH + c)) * CH + threadIdx.x + 256] = (f16)(q1 * inv);
  if (threadIdx.x == 0) ab3[b * CH + c] = sb * inv;
}

__global__ __launch_bounds__(256) void dwconv_add(const float* __restrict__ x, const float* __restrict__ wg,
                                                  const float* __restrict__ bg, float* __restrict__ out) {
  const int b = blockIdx.y, c = blockIdx.x;
  __shared__ float img[IH][IW + 1];
  const float* p = x + ((long)(b * CH + c)) * HW;
  for (int i = threadIdx.x; i < HW; i += 256) img[i >> 6][i & 63] = p[i];
  __syncthreads();
  float w[3][3];
#pragma unroll
  for (int k = 0; k < 9; ++k) w[k / 3][k % 3] = wg[c * 9 + k];
  const float bias = bg[c];
  float* op = out + ((long)(b * CH + c)) * HW;
  for (int i = threadIdx.x; i < HW; i += 256) {
    const int h = i >> 6, ww = i & 63;
    float acc = bias;
#pragma unroll
    for (int dy = -1; dy <= 1; ++dy) {
      const int hh = h + dy;
      if (hh < 0 || hh >= IH) continue;
#pragma unroll
      for (int dx = -1; dx <= 1; ++dx) {
        const int cc = ww + dx;
        if (cc < 0 || cc >= IW) continue;
        acc += w[dy + 1][dx + 1] * img[hh][cc];
      }
    }
    op[i] += 0.1f * acc;
  }
}

// ---------------- launch ----------------
extern "C" void kernel_launch(void* const* d_in, const int* in_sizes, int n_in, void* d_out, int out_size,
                              void* d_ws, size_t ws_size, hipStream_t stream) {
  const float* x  = (const float*)d_in[0];
  const float* w1 = (const float*)d_in[1];
  const float* b1 = (const float*)d_in[2];
  const float* w2 = (const float*)d_in[3];
  const float* b2 = (const float*)d_in[4];
  const float* w3 = (const float*)d_in[5];
  const float* b3 = (const float*)d_in[6];
  const float* wg = (const float*)d_in[7];
  const float* bg = (const float*)d_in[8];
  float* out = (float*)d_out;

  char* ws = (char*)d_ws;
  size_t off = 0;
  auto alloc = [&](size_t bytes) -> void* {
    void* p = ws + off;
    off += (bytes + 255) & ~(size_t)255;
    return p;
  };
  const long CC = (long)CH * CH;
  f16* G16h = (f16*)alloc(NB * CC * 2);
  f16* G16l = (f16*)alloc(NB * CC * 2);
  f16* P16h = (f16*)alloc(NB * CC * 2);
  f16* P16l = (f16*)alloc(NB * CC * 2);
  f16* attn16 = (f16*)alloc(NB * CC * 2);
  f16* M16 = (f16*)alloc(NB * CC * 2);
  float* scores = (float*)alloc(NB * CC * 4);
  f16* w1h = (f16*)alloc(CC * 2);
  f16* w1l = (f16*)alloc(CC * 2);
  f16* w2h = (f16*)alloc(CC * 2);
  f16* w2l = (f16*)alloc(CC * 2);
  f16* w3t = (f16*)alloc(CC * 2);
  float* sv = (float*)alloc(NB * CH * 4);
  float* tv = (float*)alloc(NB * CH * 4);
  float* uv = (float*)alloc(NB * CH * 4);
  float* ab3 = (float*)alloc(NB * CH * 4);

  const dim3 blk(256);
  // weight prep + s,t,u
  prep_w<<<dim3((CH * CH + 255) / 256), blk, 0, stream>>>(w1, w2, w3, w1h, w1l, w2h, w2l, w3t);
  rowsum_k<<<dim3(CH, NB), blk, 0, stream>>>(x, sv);
  prep_tu<<<dim3(CH, NB), blk, 0, stream>>>(w1, w2, b2, sv, tv, uv);

  // K1: Gram G = x x^T (hi/lo split), K = 4096
  gemm_k<1, 1, true, 0><<<dim3(CH / BM, CH / BN, NB), blk, 0, stream>>>(
      x, nullptr, (long)CH * HW, HW, x, nullptr, (long)CH * HW, HW, G16h, G16l, CC, CH, HW,
      nullptr, nullptr, nullptr, nullptr);
  // K2a: P = W1 * G  (split), G symmetric so [n][k] tile == G
  gemm_k<0, 0, true, 0><<<dim3(CH / BM, CH / BN, NB), blk, 0, stream>>>(
      w1h, w1l, 0, CH, G16h, G16l, CC, CH, P16h, P16l, CC, CH, CH,
      nullptr, nullptr, nullptr, nullptr);
  // K2b: scores = P * W2^T + b1 u^T + t b2^T  (split)
  gemm_k<0, 0, true, 1><<<dim3(CH / BM, CH / BN, NB), blk, 0, stream>>>(
      P16h, P16l, CC, CH, w2h, w2l, 0, CH, scores, nullptr, CC, CH, CH, b1, uv, tv, b2);
  // softmax rows -> attn16, ab3
  softmax_k<<<dim3(CH, NB), blk, 0, stream>>>(scores, b3, attn16, ab3);
  // K4: M = attn * W3   (B-frag reads W3^T tile)
  gemm_k<0, 0, false, 2><<<dim3(CH / BM, CH / BN, NB), blk, 0, stream>>>(
      attn16, nullptr, CC, CH, w3t, nullptr, 0, CH, M16, nullptr, CC, CH, CH,
      nullptr, nullptr, nullptr, nullptr);
  // K5: out = x + 0.1*(M x + ab3)   (B = x, transposed staging)
  gemm_k<0, 2, false, 3><<<dim3(CH / BM, HW / BN, NB), blk, 0, stream>>>(
      M16, nullptr, CC, CH, x, nullptr, (long)CH * HW, HW, out, nullptr, (long)CH * HW, HW, CH,
      x, ab3, nullptr, nullptr);
  // K6: out += 0.1 * (depthwise 3x3 + bg)
  dwconv_add<<<dim3(CH, NB), blk, 0, stream>>>(x, wg, bg, out);
}

// Round 4
// 381.743 us; speedup vs baseline: 1.3407x; 1.3407x over previous
//
#include <hip/hip_runtime.h>

typedef _Float16 f16;
typedef _Float16 half8 __attribute__((ext_vector_type(8)));
typedef _Float16 half4 __attribute__((ext_vector_type(4)));
typedef float    f32x4 __attribute__((ext_vector_type(4)));

#define DEV static __device__ __forceinline__

constexpr int NB = 8, CH = 512, HW = 4096, IH = 64, IW = 64;

typedef const __attribute__((address_space(1))) void gas_void;
typedef __attribute__((address_space(3))) void       las_void;

// ---- async staging: f16 global [rows][ld] -> linear LDS [rows][64] ----
// LDS dest = wave-uniform base (i*512 halves) + lane*16B: exactly the
// global_load_lds contract (guide §5 caveat / m104).
template <int ROWS>
DEV void stage_gll(f16* lds, const f16* src, long ld) {
  const int lane = threadIdx.x & 63, w = threadIdx.x >> 6;
  const int r8 = lane >> 3, c16 = lane & 7;
#pragma unroll
  for (int i = w; i < (ROWS / 8); i += 4) {
    const f16* g = src + (long)(i * 8 + r8) * ld + c16 * 8;
    __builtin_amdgcn_global_load_lds((gas_void*)g, (las_void*)(lds + i * 512 + lane * 8), 16, 0, 0);
  }
}

// ---------------- m97-style MFMA GEMM ----------------
// O = A(MxK)*B(KxN); A,B staged [outdim][k] f16 (hi + optional lo split).
// C/D frag mapping: col = lane&15, row = (lane>>4)*4 + j  [verified m89/m91].
// EPI: 0 = split f16 write (O1 hi, O2 lo); 1 = f32 + rank1(e0*e1 + e2*e3);
//      2 = f16; 3 = O1 += 0.1*(acc + e1[row]); 5 = f32 atomicAdd (split-K partial).
// TRI: blockIdx.x indexes upper-triangle 128-tile pairs (Gram).
template <int BM, int BN, bool SPLIT, int KS, int EPI, bool TRI>
__global__ __launch_bounds__(256, 2) void gemm2(
    const f16* __restrict__ Ah, const f16* __restrict__ Al, long sAb, int lda,
    const f16* __restrict__ Bh, const f16* __restrict__ Bl, long sBb, int ldb,
    void* __restrict__ O1, void* __restrict__ O2, long sOb, int ldo, int K,
    const float* __restrict__ e0, const float* __restrict__ e1,
    const float* __restrict__ e2, const float* __restrict__ e3) {
  constexpr int FM = BM / 32, FN = BN / 32;
  __shared__ f16 sAh[BM * 64], sBh[BN * 64];
  __shared__ f16 sAl[SPLIT ? BM * 64 : 1], sBl[SPLIT ? BN * 64 : 1];

  int bx = blockIdx.x, by = blockIdx.y;
  if constexpr (TRI) {  // t -> (mi,ni), 0<=mi<=ni<4
    int t = blockIdx.x, mi = 0;
    while (t >= 4 - mi) { t -= 4 - mi; ++mi; }
    bx = mi; by = mi + t;
  }
  const int bz = blockIdx.z, b = bz / KS, ks = bz % KS;
  const int m0 = bx * BM, n0 = by * BN;
  const int lane = threadIdx.x & 63, wave = threadIdx.x >> 6;
  const int wr = (wave >> 1) * (BM / 2), wc = (wave & 1) * (BN / 2);
  const int fr = lane & 15, fq = lane >> 4;

  const f16* Ab  = Ah + b * sAb + (long)m0 * lda;
  const f16* Bb  = Bh + b * sBb + (long)n0 * ldb;
  const f16* Ab2 = SPLIT ? Al + b * sAb + (long)m0 * lda : nullptr;
  const f16* Bb2 = SPLIT ? Bl + b * sBb + (long)n0 * ldb : nullptr;

  f32x4 acc[FM][FN] = {};
  const int kbeg = ks * K, kend = kbeg + K;
  for (int k0 = kbeg; k0 < kend; k0 += 64) {
    stage_gll<BM>(sAh, Ab + k0, lda);
    stage_gll<BN>(sBh, Bb + k0, ldb);
    if constexpr (SPLIT) {
      stage_gll<BM>(sAl, Ab2 + k0, lda);
      stage_gll<BN>(sBl, Bb2 + k0, ldb);
    }
    __syncthreads();
#pragma unroll
    for (int kk = 0; kk < 2; ++kk) {
      half8 ah[FM], bh[FN];
#pragma unroll
      for (int mi = 0; mi < FM; ++mi)
        ah[mi] = *(const half8*)&sAh[(wr + mi * 16 + fr) * 64 + kk * 32 + fq * 8];
#pragma unroll
      for (int ni = 0; ni < FN; ++ni)
        bh[ni] = *(const half8*)&sBh[(wc + ni * 16 + fr) * 64 + kk * 32 + fq * 8];
      if constexpr (SPLIT) {
        half8 al[FM], bl[FN];
#pragma unroll
        for (int mi = 0; mi < FM; ++mi)
          al[mi] = *(const half8*)&sAl[(wr + mi * 16 + fr) * 64 + kk * 32 + fq * 8];
#pragma unroll
        for (int ni = 0; ni < FN; ++ni)
          bl[ni] = *(const half8*)&sBl[(wc + ni * 16 + fr) * 64 + kk * 32 + fq * 8];
#pragma unroll
        for (int mi = 0; mi < FM; ++mi)
#pragma unroll
          for (int ni = 0; ni < FN; ++ni) {
            acc[mi][ni] = __builtin_amdgcn_mfma_f32_16x16x32_f16(ah[mi], bh[ni], acc[mi][ni], 0, 0, 0);
            acc[mi][ni] = __builtin_amdgcn_mfma_f32_16x16x32_f16(ah[mi], bl[ni], acc[mi][ni], 0, 0, 0);
            acc[mi][ni] = __builtin_amdgcn_mfma_f32_16x16x32_f16(al[mi], bh[ni], acc[mi][ni], 0, 0, 0);
          }
      } else {
#pragma unroll
        for (int mi = 0; mi < FM; ++mi)
#pragma unroll
          for (int ni = 0; ni < FN; ++ni)
            acc[mi][ni] = __builtin_amdgcn_mfma_f32_16x16x32_f16(ah[mi], bh[ni], acc[mi][ni], 0, 0, 0);
      }
    }
    __syncthreads();
  }

#pragma unroll
  for (int mi = 0; mi < FM; ++mi)
#pragma unroll
    for (int ni = 0; ni < FN; ++ni)
#pragma unroll
      for (int j = 0; j < 4; ++j) {
        const int row = m0 + wr + mi * 16 + fq * 4 + j;
        const int col = n0 + wc + ni * 16 + fr;
        float g = acc[mi][ni][j];
        const long oi = b * sOb + (long)row * ldo + col;
        if constexpr (EPI == 0) {
          f16 h = (f16)g;
          ((f16*)O1)[oi] = h;
          ((f16*)O2)[oi] = (f16)(g - (float)h);
        } else if constexpr (EPI == 1) {
          g += e0[row] * e1[b * CH + col] + e2[b * CH + row] * e3[col];
          ((float*)O1)[oi] = g;
        } else if constexpr (EPI == 2) {
          ((f16*)O1)[oi] = (f16)g;
        } else if constexpr (EPI == 3) {
          ((float*)O1)[oi] += 0.1f * (g + e1[b * CH + row]);
        } else {
          unsafeAtomicAdd(&((float*)O1)[oi], g);
        }
      }
}

// ---------------- reductions ----------------
template <int OP>  // 0 = sum, 1 = max
DEV float blockReduce(float v) {
#pragma unroll
  for (int o = 32; o; o >>= 1) {
    float w = __shfl_xor(v, o);
    v = OP ? fmaxf(v, w) : v + w;
  }
  __shared__ float t[4];
  __shared__ float res;
  __syncthreads();
  if ((threadIdx.x & 63) == 0) t[threadIdx.x >> 6] = v;
  __syncthreads();
  if (threadIdx.x == 0)
    res = OP ? fmaxf(fmaxf(t[0], t[1]), fmaxf(t[2], t[3])) : t[0] + t[1] + t[2] + t[3];
  __syncthreads();
  return res;
}

// ---------------- prep / small kernels ----------------
// x (f32 [B][C][HW]) -> xh,xl (f16 same layout) + xT (f16 [B][HW][C], hi)
__global__ __launch_bounds__(256) void convert_x(const float* __restrict__ x, f16* __restrict__ xh,
                                                 f16* __restrict__ xl, f16* __restrict__ xT) {
  const int p0 = blockIdx.x * 64, c0 = blockIdx.y * 64, b = blockIdx.z;
  __shared__ f16 tl[64][72];  // [pixel][chan]
  const int t = threadIdx.x;
  const int rr0 = t >> 4, c4 = (t & 15) * 4;
  const float* xb = x + (long)b * CH * HW;
#pragma unroll
  for (int i = 0; i < 4; ++i) {
    const int r = rr0 + i * 16;  // channel within tile
    f32x4 v = *(const f32x4*)(xb + (long)(c0 + r) * HW + p0 + c4);
    half4 h, l;
#pragma unroll
    for (int j = 0; j < 4; ++j) {
      f16 hi = (f16)v[j];
      h[j] = hi;
      l[j] = (f16)(v[j] - (float)hi);
      tl[c4 + j][r] = hi;
    }
    *(half4*)(xh + ((long)b * CH + c0 + r) * HW + p0 + c4) = h;
    *(half4*)(xl + ((long)b * CH + c0 + r) * HW + p0 + c4) = l;
  }
  __syncthreads();
  const int pr = t >> 2, cc = (t & 3) * 16;
  f16* dst = xT + ((long)b * HW + p0 + pr) * CH + c0 + cc;
  *(half8*)dst       = *(half8*)&tl[pr][cc];
  *(half8*)(dst + 8) = *(half8*)&tl[pr][cc + 8];
}

// G32 (f32, valid where tile128(r)<=tile128(c)) -> mirrored hi/lo f16
__global__ __launch_bounds__(256) void cvt_g(const float* __restrict__ G32, f16* __restrict__ Gh,
                                             f16* __restrict__ Gl) {
  const int c0 = blockIdx.x * 64, r0 = blockIdx.y * 64, b = blockIdx.z;
  const bool lower = (r0 >> 7) > (c0 >> 7);
  __shared__ float tl[64][65];
  const int t = threadIdx.x;
  const int rr0 = t >> 4, c4 = (t & 15) * 4;
  const float* Gb = G32 + (long)b * CH * CH;
  if (lower) {
#pragma unroll
    for (int i = 0; i < 4; ++i) {
      const int r = rr0 + i * 16;
      f32x4 v = *(const f32x4*)(Gb + (long)(c0 + r) * CH + r0 + c4);
#pragma unroll
      for (int j = 0; j < 4; ++j) tl[c4 + j][r] = v[j];
    }
    __syncthreads();
  }
#pragma unroll
  for (int i = 0; i < 4; ++i) {
    const int r = rr0 + i * 16;
    f32x4 v;
    if (lower)
      v = *(const f32x4*)&tl[r][c4];
    else
      v = *(const f32x4*)(Gb + (long)(r0 + r) * CH + c0 + c4);
    half4 h, l;
#pragma unroll
    for (int j = 0; j < 4; ++j) {
      f16 hi = (f16)v[j];
      h[j] = hi;
      l[j] = (f16)(v[j] - (float)hi);
    }
    *(half4*)(Gh + ((long)b * CH + r0 + r) * CH + c0 + c4) = h;
    *(half4*)(Gl + ((long)b * CH + r0 + r) * CH + c0 + c4) = l;
  }
}

__global__ __launch_bounds__(256) void prep_w(const float* __restrict__ w1, const float* __restrict__ w2,
                                              const float* __restrict__ w3, f16* w1h, f16* w1l, f16* w2h,
                                              f16* w2l, f16* w3t) {
  const int i = blockIdx.x * 256 + threadIdx.x;
  if (i >= CH * CH) return;
  float a = w1[i];
  f16 h = (f16)a;
  w1h[i] = h;
  w1l[i] = (f16)(a - (float)h);
  float bv = w2[i];
  h = (f16)bv;
  w2h[i] = h;
  w2l[i] = (f16)(bv - (float)h);
  const int r = i >> 9, c = i & 511;
  w3t[c * CH + r] = (f16)w3[i];
}

__global__ __launch_bounds__(256) void rowsum_k(const float* __restrict__ x, float* __restrict__ s) {
  const int b = blockIdx.y, c = blockIdx.x;
  const float* p = x + ((long)(b * CH + c)) * HW;
  float a = 0.f;
  for (int i = threadIdx.x; i < HW; i += 256) a += p[i];
  a = blockReduce<0>(a);
  if (threadIdx.x == 0) s[b * CH + c] = a;
}

__global__ __launch_bounds__(256) void prep_tu(const float* __restrict__ w1, const float* __restrict__ w2,
                                               const float* __restrict__ b2, const float* __restrict__ s,
                                               float* __restrict__ t, float* __restrict__ u) {
  const int b = blockIdx.y, c = blockIdx.x;
  float a1 = 0.f, a2 = 0.f;
  for (int i = threadIdx.x; i < CH; i += 256) {
    float sv = s[b * CH + i];
    a1 += w1[(long)c * CH + i] * sv;
    a2 += w2[(long)c * CH + i] * sv;
  }
  a1 = blockReduce<0>(a1);
  a2 = blockReduce<0>(a2);
  if (threadIdx.x == 0) {
    t[b * CH + c] = a1;
    u[b * CH + c] = a2 + (float)HW * b2[c];
  }
}

__global__ __launch_bounds__(256) void softmax_k(const float* __restrict__ sc, const float* __restrict__ b3,
                                                 f16* __restrict__ attn, float* __restrict__ ab3) {
  const int b = blockIdx.y, c = blockIdx.x;
  const float* row = sc + ((long)(b * CH + c)) * CH;
  const float v0 = row[threadIdx.x], v1 = row[threadIdx.x + 256];
  const float m = blockReduce<1>(fmaxf(v0, v1));
  const float q0 = __expf(v0 - m), q1 = __expf(v1 - m);
  const float sum = blockReduce<0>(q0 + q1);
  const float sb = blockReduce<0>(q0 * b3[threadIdx.x] + q1 * b3[threadIdx.x + 256]);
  const float inv = 1.f / sum;
  attn[((long)(b * CH + c)) * CH + threadIdx.x] = (f16)(q0 * inv);
  attn[((long)(b * CH + c)) * CH + threadIdx.x + 256] = (f16)(q1 * inv);
  if (threadIdx.x == 0) ab3[b * CH + c] = sb * inv;
}

// out = x + 0.1*(depthwise3x3(x) + bg)   (write-only; K5 adds the attention term)
__global__ __launch_bounds__(256) void dwconv_k(const float* __restrict__ x, const float* __restrict__ wg,
                                                const float* __restrict__ bg, float* __restrict__ out) {
  const int b = blockIdx.y, c = blockIdx.x;
  __shared__ float img[IH][IW + 1];
  const float* p = x + ((long)(b * CH + c)) * HW;
  for (int i = threadIdx.x; i < HW; i += 256) img[i >> 6][i & 63] = p[i];
  __syncthreads();
  float w[3][3];
#pragma unroll
  for (int k = 0; k < 9; ++k) w[k / 3][k % 3] = wg[c * 9 + k];
  const float bias = bg[c];
  float* op = out + ((long)(b * CH + c)) * HW;
  for (int i = threadIdx.x; i < HW; i += 256) {
    const int h = i >> 6, ww = i & 63;
    float acc = bias;
#pragma unroll
    for (int dy = -1; dy <= 1; ++dy) {
      const int hh = h + dy;
      if (hh < 0 || hh >= IH) continue;
#pragma unroll
      for (int dx = -1; dx <= 1; ++dx) {
        const int cc2 = ww + dx;
        if (cc2 < 0 || cc2 >= IW) continue;
        acc += w[dy + 1][dx + 1] * img[hh][cc2];
      }
    }
    op[i] = img[h][ww] + 0.1f * acc;
  }
}

// ---------------- launch ----------------
extern "C" void kernel_launch(void* const* d_in, const int* in_sizes, int n_in, void* d_out, int out_size,
                              void* d_ws, size_t ws_size, hipStream_t stream) {
  const float* x  = (const float*)d_in[0];
  const float* w1 = (const float*)d_in[1];
  const float* b1 = (const float*)d_in[2];
  const float* w2 = (const float*)d_in[3];
  const float* b2 = (const float*)d_in[4];
  const float* w3 = (const float*)d_in[5];
  const float* b3 = (const float*)d_in[6];
  const float* wg = (const float*)d_in[7];
  const float* bg = (const float*)d_in[8];
  float* out = (float*)d_out;

  char* ws = (char*)d_ws;
  size_t off = 0;
  auto alloc = [&](size_t bytes) -> void* {
    void* p = ws + off;
    off += (bytes + 255) & ~(size_t)255;
    return p;
  };
  const long CC = (long)CH * CH;
  const long CHW = (long)CH * HW;
  f16* xh  = (f16*)alloc(NB * CHW * 2);
  f16* xl  = (f16*)alloc(NB * CHW * 2);
  f16* xT  = (f16*)alloc(NB * CHW * 2);
  float* G32 = (float*)alloc(NB * CC * 4);
  f16* G16h = (f16*)alloc(NB * CC * 2);
  f16* G16l = (f16*)alloc(NB * CC * 2);
  f16* P16h = (f16*)alloc(NB * CC * 2);
  f16* P16l = (f16*)alloc(NB * CC * 2);
  f16* w1h = (f16*)alloc(CC * 2);
  f16* w1l = (f16*)alloc(CC * 2);
  f16* w2h = (f16*)alloc(CC * 2);
  f16* w2l = (f16*)alloc(CC * 2);
  f16* w3t = (f16*)alloc(CC * 2);
  float* sv = (float*)alloc(NB * CH * 4);
  float* tv = (float*)alloc(NB * CH * 4);
  float* uv = (float*)alloc(NB * CH * 4);
  float* ab3 = (float*)alloc(NB * CH * 4);
  // disjoint-liveness aliases (strictly stream-ordered producer -> consumer):
  float* scores = G32;    // G32 dead after cvt_g; scores written 2 dispatches later
  f16* attn16 = G16h;     // G16h dead after P-gemm; attn written by softmax after
  f16* M16    = G16l;     // G16l dead after P-gemm; M written by M-gemm after

  const dim3 blk(256);

  prep_w<<<dim3((CH * CH + 255) / 256), blk, 0, stream>>>(w1, w2, w3, w1h, w1l, w2h, w2l, w3t);
  convert_x<<<dim3(HW / 64, CH / 64, NB), blk, 0, stream>>>(x, xh, xl, xT);
  rowsum_k<<<dim3(CH, NB), blk, 0, stream>>>(x, sv);
  prep_tu<<<dim3(CH, NB), blk, 0, stream>>>(w1, w2, b2, sv, tv, uv);
  hipMemsetAsync(G32, 0, NB * CC * 4, stream);

  // Gram: G = x x^T, upper 128-tiles, split-K8, f32 atomic accumulate
  gemm2<128, 128, true, 8, 5, true><<<dim3(10, 1, NB * 8), blk, 0, stream>>>(
      xh, xl, CHW, HW, xh, xl, CHW, HW, G32, nullptr, CC, CH, HW / 8,
      nullptr, nullptr, nullptr, nullptr);
  // mirror + hi/lo split
  cvt_g<<<dim3(8, 8, NB), blk, 0, stream>>>(G32, G16h, G16l);
  // P = W1 * G (split; G symmetric so [n][k] tile == G)
  gemm2<128, 64, true, 1, 0, false><<<dim3(4, 8, NB), blk, 0, stream>>>(
      w1h, w1l, 0, CH, G16h, G16l, CC, CH, P16h, P16l, CC, CH, CH,
      nullptr, nullptr, nullptr, nullptr);
  // scores = P * W2^T + b1 u^T + t b2^T (split)
  gemm2<128, 64, true, 1, 1, false><<<dim3(4, 8, NB), blk, 0, stream>>>(
      P16h, P16l, CC, CH, w2h, w2l, 0, CH, scores, nullptr, CC, CH, CH, b1, uv, tv, b2);
  softmax_k<<<dim3(CH, NB), blk, 0, stream>>>(scores, b3, attn16, ab3);
  // M = attn * W3
  gemm2<128, 64, false, 1, 2, false><<<dim3(4, 8, NB), blk, 0, stream>>>(
      attn16, nullptr, CC, CH, w3t, nullptr, 0, CH, M16, nullptr, CC, CH, CH,
      nullptr, nullptr, nullptr, nullptr);
  // out = x + 0.1*(local + bg)
  dwconv_k<<<dim3(CH, NB), blk, 0, stream>>>(x, wg, bg, out);
  // out += 0.1*(M x + ab3)
  gemm2<128, 128, false, 1, 3, false><<<dim3(4, HW / 128, NB), blk, 0, stream>>>(
      M16, nullptr, CC, CH, xT, nullptr, CHW, CH, out, nullptr, CHW, HW, CH,
      nullptr, ab3, nullptr, nullptr);
}

// Round 5
// 344.509 us; speedup vs baseline: 1.4856x; 1.1081x over previous
//
#include <hip/hip_runtime.h>

typedef _Float16 f16;
typedef _Float16 half8 __attribute__((ext_vector_type(8)));
typedef _Float16 half4 __attribute__((ext_vector_type(4)));
typedef float    f32x4 __attribute__((ext_vector_type(4)));

#define DEV static __device__ __forceinline__

constexpr int NB = 8, CH = 512, HW = 4096, IH = 64, IW = 64;

typedef const __attribute__((address_space(1))) void gas_void;
typedef __attribute__((address_space(3))) void       las_void;

// ---- async staging: f16 global [rows][ld] -> linear LDS [rows][64] ----
template <int ROWS>
DEV void stage_gll(f16* lds, const f16* src, long ld) {
  const int lane = threadIdx.x & 63, w = threadIdx.x >> 6;
  const int r8 = lane >> 3, c16 = lane & 7;
#pragma unroll
  for (int i = w; i < (ROWS / 8); i += 4) {
    const f16* g = src + (long)(i * 8 + r8) * ld + c16 * 8;
    __builtin_amdgcn_global_load_lds((gas_void*)g, (las_void*)(lds + i * 512 + lane * 8), 16, 0, 0);
  }
}

// ---------------- m97-style MFMA GEMM ----------------
// O = A(MxK)*B(KxN); A,B staged [outdim][k] f16 (hi + optional lo split).
// C/D frag mapping: col = lane&15, row = (lane>>4)*4 + j  [verified m89/m91].
// EPI: 0 = split f16 write (O1 hi, O2 lo); 1 = f32 + rank1(e0*e1 + e2*e3);
//      2 = f16; 5 = f32 atomicAdd (split-K partial).
// TRI: blockIdx.x indexes upper-triangle 128-tile pairs (Gram); diagonal
//      tiles reuse the A-stage as B (A-tile == B-tile).
template <int BM, int BN, bool SPLIT, int KS, int EPI, bool TRI>
__global__ __launch_bounds__(256, 2) void gemm2(
    const f16* __restrict__ Ah, const f16* __restrict__ Al, long sAb, int lda,
    const f16* __restrict__ Bh, const f16* __restrict__ Bl, long sBb, int ldb,
    void* __restrict__ O1, void* __restrict__ O2, long sOb, int ldo, int K,
    const float* __restrict__ e0, const float* __restrict__ e1,
    const float* __restrict__ e2, const float* __restrict__ e3) {
  constexpr int FM = BM / 32, FN = BN / 32;
  __shared__ f16 sAh[BM * 64], sBh[BN * 64];
  __shared__ f16 sAl[SPLIT ? BM * 64 : 1], sBl[SPLIT ? BN * 64 : 1];

  int bx = blockIdx.x, by = blockIdx.y;
  if constexpr (TRI) {  // t -> (mi,ni), 0<=mi<=ni<4
    int t = blockIdx.x, mi = 0;
    while (t >= 4 - mi) { t -= 4 - mi; ++mi; }
    bx = mi; by = mi + t;
  }
  const bool diag = TRI && (bx == by);
  const int bz = blockIdx.z, b = bz / KS, ks = bz % KS;
  const int m0 = bx * BM, n0 = by * BN;
  const int lane = threadIdx.x & 63, wave = threadIdx.x >> 6;
  const int wr = (wave >> 1) * (BM / 2), wc = (wave & 1) * (BN / 2);
  const int fr = lane & 15, fq = lane >> 4;

  const f16* Ab  = Ah + b * sAb + (long)m0 * lda;
  const f16* Bb  = Bh + b * sBb + (long)n0 * ldb;
  const f16* Ab2 = SPLIT ? Al + b * sAb + (long)m0 * lda : nullptr;
  const f16* Bb2 = SPLIT ? Bl + b * sBb + (long)n0 * ldb : nullptr;

  const f16* pBh = diag ? sAh : sBh;   // diagonal Gram tile: B == A
  const f16* pBl = diag ? sAl : sBl;

  f32x4 acc[FM][FN] = {};
  const int kbeg = ks * K, kend = kbeg + K;
  for (int k0 = kbeg; k0 < kend; k0 += 64) {
    stage_gll<BM>(sAh, Ab + k0, lda);
    if (!diag) stage_gll<BN>(sBh, Bb + k0, ldb);
    if constexpr (SPLIT) {
      stage_gll<BM>(sAl, Ab2 + k0, lda);
      if (!diag) stage_gll<BN>(sBl, Bb2 + k0, ldb);
    }
    __syncthreads();
#pragma unroll
    for (int kk = 0; kk < 2; ++kk) {
      half8 ah[FM], bh[FN];
#pragma unroll
      for (int mi = 0; mi < FM; ++mi)
        ah[mi] = *(const half8*)&sAh[(wr + mi * 16 + fr) * 64 + kk * 32 + fq * 8];
#pragma unroll
      for (int ni = 0; ni < FN; ++ni)
        bh[ni] = *(const half8*)&pBh[(wc + ni * 16 + fr) * 64 + kk * 32 + fq * 8];
      if constexpr (SPLIT) {
        half8 al[FM], bl[FN];
#pragma unroll
        for (int mi = 0; mi < FM; ++mi)
          al[mi] = *(const half8*)&sAl[(wr + mi * 16 + fr) * 64 + kk * 32 + fq * 8];
#pragma unroll
        for (int ni = 0; ni < FN; ++ni)
          bl[ni] = *(const half8*)&pBl[(wc + ni * 16 + fr) * 64 + kk * 32 + fq * 8];
#pragma unroll
        for (int mi = 0; mi < FM; ++mi)
#pragma unroll
          for (int ni = 0; ni < FN; ++ni) {
            acc[mi][ni] = __builtin_amdgcn_mfma_f32_16x16x32_f16(ah[mi], bh[ni], acc[mi][ni], 0, 0, 0);
            acc[mi][ni] = __builtin_amdgcn_mfma_f32_16x16x32_f16(ah[mi], bl[ni], acc[mi][ni], 0, 0, 0);
            acc[mi][ni] = __builtin_amdgcn_mfma_f32_16x16x32_f16(al[mi], bh[ni], acc[mi][ni], 0, 0, 0);
          }
      } else {
#pragma unroll
        for (int mi = 0; mi < FM; ++mi)
#pragma unroll
          for (int ni = 0; ni < FN; ++ni)
            acc[mi][ni] = __builtin_amdgcn_mfma_f32_16x16x32_f16(ah[mi], bh[ni], acc[mi][ni], 0, 0, 0);
      }
    }
    __syncthreads();
  }

#pragma unroll
  for (int mi = 0; mi < FM; ++mi)
#pragma unroll
    for (int ni = 0; ni < FN; ++ni)
#pragma unroll
      for (int j = 0; j < 4; ++j) {
        const int row = m0 + wr + mi * 16 + fq * 4 + j;
        const int col = n0 + wc + ni * 16 + fr;
        float g = acc[mi][ni][j];
        const long oi = b * sOb + (long)row * ldo + col;
        if constexpr (EPI == 0) {
          f16 h = (f16)g;
          ((f16*)O1)[oi] = h;
          ((f16*)O2)[oi] = (f16)(g - (float)h);
        } else if constexpr (EPI == 1) {
          g += e0[row] * e1[b * CH + col] + e2[b * CH + row] * e3[col];
          ((float*)O1)[oi] = g;
        } else if constexpr (EPI == 2) {
          ((f16*)O1)[oi] = (f16)g;
        } else {
          unsafeAtomicAdd(&((float*)O1)[oi], g);
        }
      }
}

// ---------------- reductions ----------------
template <int OP>  // 0 = sum, 1 = max
DEV float blockReduce(float v) {
#pragma unroll
  for (int o = 32; o; o >>= 1) {
    float w = __shfl_xor(v, o);
    v = OP ? fmaxf(v, w) : v + w;
  }
  __shared__ float t[4];
  __shared__ float res;
  __syncthreads();
  if ((threadIdx.x & 63) == 0) t[threadIdx.x >> 6] = v;
  __syncthreads();
  if (threadIdx.x == 0)
    res = OP ? fmaxf(fmaxf(t[0], t[1]), fmaxf(t[2], t[3])) : t[0] + t[1] + t[2] + t[3];
  __syncthreads();
  return res;
}

// ---------------- prep / small kernels ----------------
// x (f32 [B][C][HW]) -> xh,xl (f16) + xT (f16 [B][HW][C]) + fused rowsum -> sv
__global__ __launch_bounds__(256) void convert_x(const float* __restrict__ x, f16* __restrict__ xh,
                                                 f16* __restrict__ xl, f16* __restrict__ xT,
                                                 float* __restrict__ sv) {
  const int p0 = blockIdx.x * 64, c0 = blockIdx.y * 64, b = blockIdx.z;
  __shared__ f16 tl[64][72];  // [pixel][chan]
  const int t = threadIdx.x;
  const int rr0 = t >> 4, c4 = (t & 15) * 4;
  const float* xb = x + (long)b * CH * HW;
#pragma unroll
  for (int i = 0; i < 4; ++i) {
    const int r = rr0 + i * 16;  // channel within tile
    f32x4 v = *(const f32x4*)(xb + (long)(c0 + r) * HW + p0 + c4);
    half4 h, l;
#pragma unroll
    for (int j = 0; j < 4; ++j) {
      f16 hi = (f16)v[j];
      h[j] = hi;
      l[j] = (f16)(v[j] - (float)hi);
      tl[c4 + j][r] = hi;
    }
    *(half4*)(xh + ((long)b * CH + c0 + r) * HW + p0 + c4) = h;
    *(half4*)(xl + ((long)b * CH + c0 + r) * HW + p0 + c4) = l;
    // fused row-sum: 16 threads (same t>>4) hold this chan's 64 pixels
    float s4 = v[0] + v[1] + v[2] + v[3];
    s4 += __shfl_xor(s4, 1);
    s4 += __shfl_xor(s4, 2);
    s4 += __shfl_xor(s4, 4);
    s4 += __shfl_xor(s4, 8);
    if ((t & 15) == 0) unsafeAtomicAdd(&sv[(long)b * CH + c0 + r], s4);
  }
  __syncthreads();
  const int pr = t >> 2, cc = (t & 3) * 16;
  f16* dst = xT + ((long)b * HW + p0 + pr) * CH + c0 + cc;
  *(half8*)dst       = *(half8*)&tl[pr][cc];
  *(half8*)(dst + 8) = *(half8*)&tl[pr][cc + 8];
}

// G32 (f32, valid where tile128(r)<=tile128(c)) -> mirrored hi/lo f16
__global__ __launch_bounds__(256) void cvt_g(const float* __restrict__ G32, f16* __restrict__ Gh,
                                             f16* __restrict__ Gl) {
  const int c0 = blockIdx.x * 64, r0 = blockIdx.y * 64, b = blockIdx.z;
  const bool lower = (r0 >> 7) > (c0 >> 7);
  __shared__ float tl[64][65];
  const int t = threadIdx.x;
  const int rr0 = t >> 4, c4 = (t & 15) * 4;
  const float* Gb = G32 + (long)b * CH * CH;
  if (lower) {
#pragma unroll
    for (int i = 0; i < 4; ++i) {
      const int r = rr0 + i * 16;
      f32x4 v = *(const f32x4*)(Gb + (long)(c0 + r) * CH + r0 + c4);
#pragma unroll
      for (int j = 0; j < 4; ++j) tl[c4 + j][r] = v[j];
    }
    __syncthreads();
  }
#pragma unroll
  for (int i = 0; i < 4; ++i) {
    const int r = rr0 + i * 16;
    f32x4 v;
    if (lower)
      v = *(const f32x4*)&tl[r][c4];
    else
      v = *(const f32x4*)(Gb + (long)(r0 + r) * CH + c0 + c4);
    half4 h, l;
#pragma unroll
    for (int j = 0; j < 4; ++j) {
      f16 hi = (f16)v[j];
      h[j] = hi;
      l[j] = (f16)(v[j] - (float)hi);
    }
    *(half4*)(Gh + ((long)b * CH + r0 + r) * CH + c0 + c4) = h;
    *(half4*)(Gl + ((long)b * CH + r0 + r) * CH + c0 + c4) = l;
  }
}

__global__ __launch_bounds__(256) void prep_w(const float* __restrict__ w1, const float* __restrict__ w2,
                                              const float* __restrict__ w3, f16* w1h, f16* w1l, f16* w2h,
                                              f16* w2l, f16* w3t) {
  const int i = blockIdx.x * 256 + threadIdx.x;
  if (i >= CH * CH) return;
  float a = w1[i];
  f16 h = (f16)a;
  w1h[i] = h;
  w1l[i] = (f16)(a - (float)h);
  float bv = w2[i];
  h = (f16)bv;
  w2h[i] = h;
  w2l[i] = (f16)(bv - (float)h);
  const int r = i >> 9, c = i & 511;
  w3t[c * CH + r] = (f16)w3[i];
}

__global__ __launch_bounds__(256) void prep_tu(const float* __restrict__ w1, const float* __restrict__ w2,
                                               const float* __restrict__ b2, const float* __restrict__ s,
                                               float* __restrict__ t, float* __restrict__ u) {
  const int b = blockIdx.y, c = blockIdx.x;
  float a1 = 0.f, a2 = 0.f;
  for (int i = threadIdx.x; i < CH; i += 256) {
    float sv = s[b * CH + i];
    a1 += w1[(long)c * CH + i] * sv;
    a2 += w2[(long)c * CH + i] * sv;
  }
  a1 = blockReduce<0>(a1);
  a2 = blockReduce<0>(a2);
  if (threadIdx.x == 0) {
    t[b * CH + c] = a1;
    u[b * CH + c] = a2 + (float)HW * b2[c];
  }
}

__global__ __launch_bounds__(256) void softmax_k(const float* __restrict__ sc, const float* __restrict__ b3,
                                                 f16* __restrict__ attn, float* __restrict__ ab3) {
  const int b = blockIdx.y, c = blockIdx.x;
  const float* row = sc + ((long)(b * CH + c)) * CH;
  const float v0 = row[threadIdx.x], v1 = row[threadIdx.x + 256];
  const float m = blockReduce<1>(fmaxf(v0, v1));
  const float q0 = __expf(v0 - m), q1 = __expf(v1 - m);
  const float sum = blockReduce<0>(q0 + q1);
  const float sb = blockReduce<0>(q0 * b3[threadIdx.x] + q1 * b3[threadIdx.x + 256]);
  const float inv = 1.f / sum;
  attn[((long)(b * CH + c)) * CH + threadIdx.x] = (f16)(q0 * inv);
  attn[((long)(b * CH + c)) * CH + threadIdx.x + 256] = (f16)(q1 * inv);
  if (threadIdx.x == 0) ab3[b * CH + c] = sb * inv;
}

// out = x + 0.1*(den + ab3 + dwconv3x3(x) + bg)   — single fused output pass
__global__ __launch_bounds__(256) void combine_k(const float* __restrict__ x, const f16* __restrict__ den,
                                                 const float* __restrict__ wg, const float* __restrict__ bg,
                                                 const float* __restrict__ ab3, float* __restrict__ out) {
  const int b = blockIdx.y, c = blockIdx.x;
  __shared__ float img[IH][IW + 1];
  const float* p = x + ((long)(b * CH + c)) * HW;
  for (int i = threadIdx.x; i < HW; i += 256) img[i >> 6][i & 63] = p[i];
  __syncthreads();
  float w[3][3];
#pragma unroll
  for (int k = 0; k < 9; ++k) w[k / 3][k % 3] = wg[c * 9 + k];
  const float base = bg[c] + ab3[b * CH + c];
  const f16* dp = den + ((long)(b * CH + c)) * HW;
  float* op = out + ((long)(b * CH + c)) * HW;
  for (int i = threadIdx.x; i < HW; i += 256) {
    const int h = i >> 6, ww = i & 63;
    float acc = base + (float)dp[i];
#pragma unroll
    for (int dy = -1; dy <= 1; ++dy) {
      const int hh = h + dy;
      if (hh < 0 || hh >= IH) continue;
#pragma unroll
      for (int dx = -1; dx <= 1; ++dx) {
        const int cc2 = ww + dx;
        if (cc2 < 0 || cc2 >= IW) continue;
        acc += w[dy + 1][dx + 1] * img[hh][cc2];
      }
    }
    op[i] = img[h][ww] + 0.1f * acc;
  }
}

// ---------------- launch ----------------
extern "C" void kernel_launch(void* const* d_in, const int* in_sizes, int n_in, void* d_out, int out_size,
                              void* d_ws, size_t ws_size, hipStream_t stream) {
  const float* x  = (const float*)d_in[0];
  const float* w1 = (const float*)d_in[1];
  const float* b1 = (const float*)d_in[2];
  const float* w2 = (const float*)d_in[3];
  const float* b2 = (const float*)d_in[4];
  const float* w3 = (const float*)d_in[5];
  const float* b3 = (const float*)d_in[6];
  const float* wg = (const float*)d_in[7];
  const float* bg = (const float*)d_in[8];
  float* out = (float*)d_out;

  char* ws = (char*)d_ws;
  size_t off = 0;
  auto alloc = [&](size_t bytes) -> void* {
    void* p = ws + off;
    off += (bytes + 255) & ~(size_t)255;
    return p;
  };
  const long CC = (long)CH * CH;
  const long CHW = (long)CH * HW;
  f16* xh  = (f16*)alloc(NB * CHW * 2);
  f16* xl  = (f16*)alloc(NB * CHW * 2);
  f16* xT  = (f16*)alloc(NB * CHW * 2);
  float* G32 = (float*)alloc(NB * CC * 4);
  f16* G16h = (f16*)alloc(NB * CC * 2);
  f16* G16l = (f16*)alloc(NB * CC * 2);
  f16* P16h = (f16*)alloc(NB * CC * 2);
  f16* P16l = (f16*)alloc(NB * CC * 2);
  f16* w1h = (f16*)alloc(CC * 2);
  f16* w1l = (f16*)alloc(CC * 2);
  f16* w2h = (f16*)alloc(CC * 2);
  f16* w2l = (f16*)alloc(CC * 2);
  f16* w3t = (f16*)alloc(CC * 2);
  float* sv = (float*)alloc(NB * CH * 4);
  float* tv = (float*)alloc(NB * CH * 4);
  float* uv = (float*)alloc(NB * CH * 4);
  float* ab3 = (float*)alloc(NB * CH * 4);
  // disjoint-liveness aliases (strictly stream-ordered producer -> consumer):
  float* scores = G32;    // G32 dead after cvt_g
  f16* attn16 = G16h;     // G16h dead after P-gemm
  f16* M16    = G16l;     // G16l dead after P-gemm
  f16* den16  = xl;       // xl dead after Gram; den written by K5 afterwards

  const dim3 blk(256);

  prep_w<<<dim3((CH * CH + 255) / 256), blk, 0, stream>>>(w1, w2, w3, w1h, w1l, w2h, w2l, w3t);
  hipMemsetAsync(sv, 0, NB * CH * 4, stream);
  convert_x<<<dim3(HW / 64, CH / 64, NB), blk, 0, stream>>>(x, xh, xl, xT, sv);
  prep_tu<<<dim3(CH, NB), blk, 0, stream>>>(w1, w2, b2, sv, tv, uv);
  hipMemsetAsync(G32, 0, NB * CC * 4, stream);

  // Gram: G = x x^T, upper 128-tiles, split-K8, f32 atomic accumulate
  gemm2<128, 128, true, 8, 5, true><<<dim3(10, 1, NB * 8), blk, 0, stream>>>(
      xh, xl, CHW, HW, xh, xl, CHW, HW, G32, nullptr, CC, CH, HW / 8,
      nullptr, nullptr, nullptr, nullptr);
  // mirror + hi/lo split
  cvt_g<<<dim3(8, 8, NB), blk, 0, stream>>>(G32, G16h, G16l);
  // P = W1 * G (split; G symmetric so [n][k] tile == G)
  gemm2<128, 64, true, 1, 0, false><<<dim3(4, 8, NB), blk, 0, stream>>>(
      w1h, w1l, 0, CH, G16h, G16l, CC, CH, P16h, P16l, CC, CH, CH,
      nullptr, nullptr, nullptr, nullptr);
  // scores = P * W2^T + b1 u^T + t b2^T (split)
  gemm2<128, 64, true, 1, 1, false><<<dim3(4, 8, NB), blk, 0, stream>>>(
      P16h, P16l, CC, CH, w2h, w2l, 0, CH, scores, nullptr, CC, CH, CH, b1, uv, tv, b2);
  softmax_k<<<dim3(CH, NB), blk, 0, stream>>>(scores, b3, attn16, ab3);
  // M = attn * W3
  gemm2<128, 64, false, 1, 2, false><<<dim3(4, 8, NB), blk, 0, stream>>>(
      attn16, nullptr, CC, CH, w3t, nullptr, 0, CH, M16, nullptr, CC, CH, CH,
      nullptr, nullptr, nullptr, nullptr);
  // den = M x   (f16 write, no RMW)
  gemm2<128, 128, false, 1, 2, false><<<dim3(4, HW / 128, NB), blk, 0, stream>>>(
      M16, nullptr, CC, CH, xT, nullptr, CHW, CH, den16, nullptr, CHW, HW, CH,
      nullptr, nullptr, nullptr, nullptr);
  // out = x + 0.1*(den + ab3 + local + bg)
  combine_k<<<dim3(CH, NB), blk, 0, stream>>>(x, den16, wg, bg, ab3, out);
}

// Round 6
// 336.996 us; speedup vs baseline: 1.5188x; 1.0223x over previous
//
#include <hip/hip_runtime.h>

typedef _Float16 f16;
typedef _Float16 half8 __attribute__((ext_vector_type(8)));
typedef _Float16 half4 __attribute__((ext_vector_type(4)));
typedef float    f32x4 __attribute__((ext_vector_type(4)));

#define DEV static __device__ __forceinline__

constexpr int NB = 8, CH = 512, HW = 4096, IH = 64, IW = 64;

typedef const __attribute__((address_space(1))) void gas_void;
typedef __attribute__((address_space(3))) void       las_void;

// ---- async staging: f16 global [rows][ld] -> linear LDS [rows][64] ----
template <int ROWS>
DEV void stage_gll(f16* lds, const f16* src, long ld) {
  const int lane = threadIdx.x & 63, w = threadIdx.x >> 6;
  const int r8 = lane >> 3, c16 = lane & 7;
#pragma unroll
  for (int i = w; i < (ROWS / 8); i += 4) {
    const f16* g = src + (long)(i * 8 + r8) * ld + c16 * 8;
    __builtin_amdgcn_global_load_lds((gas_void*)g, (las_void*)(lds + i * 512 + lane * 8), 16, 0, 0);
  }
}

// ---------------- m97-style MFMA GEMM ----------------
// O = A(MxK)*B(KxN); A,B staged [outdim][k] f16 (hi + optional lo split).
// C/D frag mapping: col = lane&15, row = (lane>>4)*4 + j  [verified m89/m91].
// EPI: 0 = split f16 write (O1 hi, O2 lo); 1 = f32 + rank1(e0*e1 + e2*e3);
//      2 = f16; 6 = f32 store into per-ks partial buffer (split-K, no atomics).
template <int BM, int BN, bool SPLIT, int KS, int EPI>
__global__ __launch_bounds__(256, 2) void gemm2(
    const f16* __restrict__ Ah, const f16* __restrict__ Al, long sAb, int lda,
    const f16* __restrict__ Bh, const f16* __restrict__ Bl, long sBb, int ldb,
    void* __restrict__ O1, void* __restrict__ O2, long sOb, int ldo, int K,
    const float* __restrict__ e0, const float* __restrict__ e1,
    const float* __restrict__ e2, const float* __restrict__ e3) {
  constexpr int FM = BM / 32, FN = BN / 32;
  __shared__ f16 sAh[BM * 64], sBh[BN * 64];
  __shared__ f16 sAl[SPLIT ? BM * 64 : 1], sBl[SPLIT ? BN * 64 : 1];

  const int bx = blockIdx.x, by = blockIdx.y;
  const int bz = blockIdx.z, b = bz / KS, ks = bz % KS;
  const int m0 = bx * BM, n0 = by * BN;
  const int lane = threadIdx.x & 63, wave = threadIdx.x >> 6;
  const int wr = (wave >> 1) * (BM / 2), wc = (wave & 1) * (BN / 2);
  const int fr = lane & 15, fq = lane >> 4;

  const f16* Ab  = Ah + b * sAb + (long)m0 * lda;
  const f16* Bb  = Bh + b * sBb + (long)n0 * ldb;
  const f16* Ab2 = SPLIT ? Al + b * sAb + (long)m0 * lda : nullptr;
  const f16* Bb2 = SPLIT ? Bl + b * sBb + (long)n0 * ldb : nullptr;

  f32x4 acc[FM][FN] = {};
  const int kbeg = ks * K, kend = kbeg + K;
  for (int k0 = kbeg; k0 < kend; k0 += 64) {
    stage_gll<BM>(sAh, Ab + k0, lda);
    stage_gll<BN>(sBh, Bb + k0, ldb);
    if constexpr (SPLIT) {
      stage_gll<BM>(sAl, Ab2 + k0, lda);
      stage_gll<BN>(sBl, Bb2 + k0, ldb);
    }
    __syncthreads();
#pragma unroll
    for (int kk = 0; kk < 2; ++kk) {
      half8 ah[FM], bh[FN];
#pragma unroll
      for (int mi = 0; mi < FM; ++mi)
        ah[mi] = *(const half8*)&sAh[(wr + mi * 16 + fr) * 64 + kk * 32 + fq * 8];
#pragma unroll
      for (int ni = 0; ni < FN; ++ni)
        bh[ni] = *(const half8*)&sBh[(wc + ni * 16 + fr) * 64 + kk * 32 + fq * 8];
      if constexpr (SPLIT) {
        half8 al[FM], bl[FN];
#pragma unroll
        for (int mi = 0; mi < FM; ++mi)
          al[mi] = *(const half8*)&sAl[(wr + mi * 16 + fr) * 64 + kk * 32 + fq * 8];
#pragma unroll
        for (int ni = 0; ni < FN; ++ni)
          bl[ni] = *(const half8*)&sBl[(wc + ni * 16 + fr) * 64 + kk * 32 + fq * 8];
#pragma unroll
        for (int mi = 0; mi < FM; ++mi)
#pragma unroll
          for (int ni = 0; ni < FN; ++ni) {
            acc[mi][ni] = __builtin_amdgcn_mfma_f32_16x16x32_f16(ah[mi], bh[ni], acc[mi][ni], 0, 0, 0);
            acc[mi][ni] = __builtin_amdgcn_mfma_f32_16x16x32_f16(ah[mi], bl[ni], acc[mi][ni], 0, 0, 0);
            acc[mi][ni] = __builtin_amdgcn_mfma_f32_16x16x32_f16(al[mi], bh[ni], acc[mi][ni], 0, 0, 0);
          }
      } else {
#pragma unroll
        for (int mi = 0; mi < FM; ++mi)
#pragma unroll
          for (int ni = 0; ni < FN; ++ni)
            acc[mi][ni] = __builtin_amdgcn_mfma_f32_16x16x32_f16(ah[mi], bh[ni], acc[mi][ni], 0, 0, 0);
      }
    }
    __syncthreads();
  }

#pragma unroll
  for (int mi = 0; mi < FM; ++mi)
#pragma unroll
    for (int ni = 0; ni < FN; ++ni)
#pragma unroll
      for (int j = 0; j < 4; ++j) {
        const int row = m0 + wr + mi * 16 + fq * 4 + j;
        const int col = n0 + wc + ni * 16 + fr;
        float g = acc[mi][ni][j];
        const long oi = b * sOb + (long)row * ldo + col;
        if constexpr (EPI == 0) {
          f16 h = (f16)g;
          ((f16*)O1)[oi] = h;
          ((f16*)O2)[oi] = (f16)(g - (float)h);
        } else if constexpr (EPI == 1) {
          g += e0[row] * e1[b * CH + col] + e2[b * CH + row] * e3[col];
          ((float*)O1)[oi] = g;
        } else if constexpr (EPI == 2) {
          ((f16*)O1)[oi] = (f16)g;
        } else {  // EPI == 6: split-K partial, per-ks buffer
          ((float*)O1)[(((long)ks * NB + b) * CH + row) * CH + col] = g;
        }
      }
}

// ---------------- reductions ----------------
template <int OP>  // 0 = sum, 1 = max
DEV float blockReduce(float v) {
#pragma unroll
  for (int o = 32; o; o >>= 1) {
    float w = __shfl_xor(v, o);
    v = OP ? fmaxf(v, w) : v + w;
  }
  __shared__ float t[4];
  __shared__ float res;
  __syncthreads();
  if ((threadIdx.x & 63) == 0) t[threadIdx.x >> 6] = v;
  __syncthreads();
  if (threadIdx.x == 0)
    res = OP ? fmaxf(fmaxf(t[0], t[1]), fmaxf(t[2], t[3])) : t[0] + t[1] + t[2] + t[3];
  __syncthreads();
  return res;
}

// ---------------- prep / small kernels ----------------
// x (f32 row) -> xh = f16(x), xm = f16(2x - xh)  (so (xh+xm)/2 carries hi+lo info)
// + exact full-row sum -> sv (no atomics)
__global__ __launch_bounds__(256) void convert1(const float* __restrict__ x, f16* __restrict__ xh,
                                                f16* __restrict__ xm, float* __restrict__ sv) {
  const int c = blockIdx.x, b = blockIdx.y;
  const long base = ((long)(b * CH + c)) * HW;
  const float* p = x + base;
  f16* ph = xh + base;
  f16* pm = xm + base;
  float s = 0.f;
#pragma unroll
  for (int i0 = 0; i0 < 4; ++i0) {
    const int i = (threadIdx.x + i0 * 256) * 4;
    f32x4 v = *(const f32x4*)(p + i);
    half4 h, m;
#pragma unroll
    for (int j = 0; j < 4; ++j) {
      f16 hi = (f16)v[j];
      h[j] = hi;
      m[j] = (f16)(2.f * v[j] - (float)hi);
      s += v[j];
    }
    *(half4*)(ph + i) = h;
    *(half4*)(pm + i) = m;
  }
  s = blockReduce<0>(s);
  if (threadIdx.x == 0) sv[b * CH + c] = s;
}

// xh [B][C][HW] -> xT [B][HW][C]  (f16 transpose via LDS)
__global__ __launch_bounds__(256) void convert2(const f16* __restrict__ xh, f16* __restrict__ xT) {
  const int p0 = blockIdx.x * 64, c0 = blockIdx.y * 64, b = blockIdx.z;
  __shared__ f16 tl[64][72];
  const int t = threadIdx.x;
  const int cr = t >> 2, pc = (t & 3) * 16;
  const f16* src = xh + ((long)(b * CH) + c0 + cr) * HW + p0 + pc;
  half8 a0 = *(const half8*)src, a1 = *(const half8*)(src + 8);
#pragma unroll
  for (int j = 0; j < 8; ++j) {
    tl[pc + j][cr] = a0[j];
    tl[pc + 8 + j][cr] = a1[j];
  }
  __syncthreads();
  f16* dst = xT + ((long)b * HW + p0 + cr) * CH + c0 + pc;
  *(half8*)dst       = *(half8*)&tl[cr][pc];
  *(half8*)(dst + 8) = *(half8*)&tl[cr][pc + 8];
}

// G = (E + E^T)/2 summed over KS partials -> hi/lo f16
template <int KS>
__global__ __launch_bounds__(256) void cvt_g(const float* __restrict__ E, f16* __restrict__ Gh,
                                             f16* __restrict__ Gl) {
  const int c0 = blockIdx.x * 64, r0 = blockIdx.y * 64, b = blockIdx.z;
  __shared__ float tl[64][65];
  const int t = threadIdx.x;
  const int rr0 = t >> 4, c4 = (t & 15) * 4;
  f32x4 acc[4] = {};
  for (int ks = 0; ks < KS; ++ks) {
    const float* Eb = E + ((long)ks * NB + b) * (long)CH * CH;
#pragma unroll
    for (int i = 0; i < 4; ++i)
      acc[i] += *(const f32x4*)(Eb + (long)(r0 + rr0 + i * 16) * CH + c0 + c4);
    __syncthreads();
#pragma unroll
    for (int i = 0; i < 4; ++i) {
      f32x4 w = *(const f32x4*)(Eb + (long)(c0 + rr0 + i * 16) * CH + r0 + c4);
#pragma unroll
      for (int j = 0; j < 4; ++j) tl[rr0 + i * 16][c4 + j] = w[j];
    }
    __syncthreads();
#pragma unroll
    for (int i = 0; i < 4; ++i)
#pragma unroll
      for (int j = 0; j < 4; ++j) acc[i][j] += tl[c4 + j][rr0 + i * 16];
  }
#pragma unroll
  for (int i = 0; i < 4; ++i) {
    half4 h, l;
#pragma unroll
    for (int j = 0; j < 4; ++j) {
      const float g = 0.5f * acc[i][j];
      f16 hi = (f16)g;
      h[j] = hi;
      l[j] = (f16)(g - (float)hi);
    }
    const long oi = ((long)b * CH + r0 + rr0 + i * 16) * CH + c0 + c4;
    *(half4*)(Gh + oi) = h;
    *(half4*)(Gl + oi) = l;
  }
}

__global__ __launch_bounds__(256) void prep_w(const float* __restrict__ w1, const float* __restrict__ w2,
                                              const float* __restrict__ w3, f16* w1h, f16* w1l, f16* w2h,
                                              f16* w2l, f16* w3t) {
  const int i = blockIdx.x * 256 + threadIdx.x;
  if (i >= CH * CH) return;
  float a = w1[i];
  f16 h = (f16)a;
  w1h[i] = h;
  w1l[i] = (f16)(a - (float)h);
  float bv = w2[i];
  h = (f16)bv;
  w2h[i] = h;
  w2l[i] = (f16)(bv - (float)h);
  const int r = i >> 9, c = i & 511;
  w3t[c * CH + r] = (f16)w3[i];
}

__global__ __launch_bounds__(256) void prep_tu(const float* __restrict__ w1, const float* __restrict__ w2,
                                               const float* __restrict__ b2, const float* __restrict__ s,
                                               float* __restrict__ t, float* __restrict__ u) {
  const int b = blockIdx.y, c = blockIdx.x;
  float a1 = 0.f, a2 = 0.f;
  for (int i = threadIdx.x; i < CH; i += 256) {
    float sv = s[b * CH + i];
    a1 += w1[(long)c * CH + i] * sv;
    a2 += w2[(long)c * CH + i] * sv;
  }
  a1 = blockReduce<0>(a1);
  a2 = blockReduce<0>(a2);
  if (threadIdx.x == 0) {
    t[b * CH + c] = a1;
    u[b * CH + c] = a2 + (float)HW * b2[c];
  }
}

__global__ __launch_bounds__(256) void softmax_k(const float* __restrict__ sc, const float* __restrict__ b3,
                                                 f16* __restrict__ attn, float* __restrict__ ab3) {
  const int b = blockIdx.y, c = blockIdx.x;
  const float* row = sc + ((long)(b * CH + c)) * CH;
  const float v0 = row[threadIdx.x], v1 = row[threadIdx.x + 256];
  const float m = blockReduce<1>(fmaxf(v0, v1));
  const float q0 = __expf(v0 - m), q1 = __expf(v1 - m);
  const float sum = blockReduce<0>(q0 + q1);
  const float sb = blockReduce<0>(q0 * b3[threadIdx.x] + q1 * b3[threadIdx.x + 256]);
  const float inv = 1.f / sum;
  attn[((long)(b * CH + c)) * CH + threadIdx.x] = (f16)(q0 * inv);
  attn[((long)(b * CH + c)) * CH + threadIdx.x + 256] = (f16)(q1 * inv);
  if (threadIdx.x == 0) ab3[b * CH + c] = sb * inv;
}

// out = x + 0.1*(den + ab3 + dwconv3x3(x) + bg)   — single fused output pass
__global__ __launch_bounds__(256) void combine_k(const float* __restrict__ x, const f16* __restrict__ den,
                                                 const float* __restrict__ wg, const float* __restrict__ bg,
                                                 const float* __restrict__ ab3, float* __restrict__ out) {
  const int b = blockIdx.y, c = blockIdx.x;
  __shared__ float img[IH][IW + 4];
  const long base = ((long)(b * CH + c)) * HW;
  const float* p = x + base;
  const int t = threadIdx.x;
  const int h0 = t >> 2, w0 = (t & 3) * 16;
#pragma unroll
  for (int k = 0; k < 4; ++k)
    *(f32x4*)&img[h0][w0 + 4 * k] = *(const f32x4*)(p + h0 * 64 + w0 + 4 * k);
  __syncthreads();
  float w[3][3];
#pragma unroll
  for (int k = 0; k < 9; ++k) w[k / 3][k % 3] = wg[c * 9 + k];
  const float bb = bg[c] + ab3[b * CH + c];
  const f16* dp = den + base;
  float* op = out + base;
#pragma unroll
  for (int k = 0; k < 4; ++k) {
    const int ww = w0 + 4 * k;
    half4 d4 = *(const half4*)(dp + h0 * 64 + ww);
    f32x4 o;
#pragma unroll
    for (int j = 0; j < 4; ++j) {
      const int wj = ww + j;
      float acc = bb + (float)d4[j];
#pragma unroll
      for (int dy = -1; dy <= 1; ++dy) {
        const int hh = h0 + dy;
        if (hh < 0 || hh >= IH) continue;
#pragma unroll
        for (int dx = -1; dx <= 1; ++dx) {
          const int cc2 = wj + dx;
          if (cc2 < 0 || cc2 >= IW) continue;
          acc += w[dy + 1][dx + 1] * img[hh][cc2];
        }
      }
      o[j] = img[h0][wj] + 0.1f * acc;
    }
    *(f32x4*)(op + h0 * 64 + ww) = o;
  }
}

// ---------------- launch ----------------
extern "C" void kernel_launch(void* const* d_in, const int* in_sizes, int n_in, void* d_out, int out_size,
                              void* d_ws, size_t ws_size, hipStream_t stream) {
  const float* x  = (const float*)d_in[0];
  const float* w1 = (const float*)d_in[1];
  const float* b1 = (const float*)d_in[2];
  const float* w2 = (const float*)d_in[3];
  const float* b2 = (const float*)d_in[4];
  const float* w3 = (const float*)d_in[5];
  const float* b3 = (const float*)d_in[6];
  const float* wg = (const float*)d_in[7];
  const float* bg = (const float*)d_in[8];
  float* out = (float*)d_out;

  char* ws = (char*)d_ws;
  size_t off = 0;
  auto alloc = [&](size_t bytes) -> void* {
    void* p = ws + off;
    off += (bytes + 255) & ~(size_t)255;
    return p;
  };
  const long CC = (long)CH * CH;
  const long CHW = (long)CH * HW;
  constexpr int GKS = 4;  // Gram split-K factor
  f16* xh    = (f16*)alloc(NB * CHW * 2);
  f16* xm    = (f16*)alloc(NB * CHW * 2);
  float* Epart = (float*)alloc((long)GKS * NB * CC * 4);
  f16* G16h = (f16*)alloc(NB * CC * 2);
  f16* G16l = (f16*)alloc(NB * CC * 2);
  f16* P16h = (f16*)alloc(NB * CC * 2);
  f16* P16l = (f16*)alloc(NB * CC * 2);
  f16* w1h = (f16*)alloc(CC * 2);
  f16* w1l = (f16*)alloc(CC * 2);
  f16* w2h = (f16*)alloc(CC * 2);
  f16* w2l = (f16*)alloc(CC * 2);
  f16* w3t = (f16*)alloc(CC * 2);
  float* sv = (float*)alloc(NB * CH * 4);
  float* tv = (float*)alloc(NB * CH * 4);
  float* uv = (float*)alloc(NB * CH * 4);
  float* ab3 = (float*)alloc(NB * CH * 4);
  // disjoint-liveness aliases (strictly stream-ordered producer -> consumer):
  f16* xT     = (f16*)Epart;              // Epart dead after cvt_g; xT built by convert2 after
  float* scores = (float*)xh;             // xh dead after convert2 (8 MB of 32)
  f16* attn16 = (f16*)((char*)xh + (NB * CC * 4));           // +8 MB, 4 MB
  f16* M16    = (f16*)((char*)xh + (NB * CC * 4) + (NB * CC * 2));  // +12 MB, 4 MB
  f16* den16  = xm;                       // xm dead after Gram

  const dim3 blk(256);

  prep_w<<<dim3((CH * CH + 255) / 256), blk, 0, stream>>>(w1, w2, w3, w1h, w1l, w2h, w2l, w3t);
  convert1<<<dim3(CH, NB), blk, 0, stream>>>(x, xh, xm, sv);
  prep_tu<<<dim3(CH, NB), blk, 0, stream>>>(w1, w2, b2, sv, tv, uv);

  // E = xh * xm^T, all 16 tile-pairs, split-K4 into per-ks partial buffers
  gemm2<128, 128, false, GKS, 6><<<dim3(4, 4, NB * GKS), blk, 0, stream>>>(
      xh, nullptr, CHW, HW, xm, nullptr, CHW, HW, Epart, nullptr, CC, CH, HW / GKS,
      nullptr, nullptr, nullptr, nullptr);
  // G = (E + E^T)/2, fold KS partials, hi/lo split
  cvt_g<GKS><<<dim3(8, 8, NB), blk, 0, stream>>>(Epart, G16h, G16l);
  // xT = transpose(xh)  (into dead Epart slot)
  convert2<<<dim3(HW / 64, CH / 64, NB), blk, 0, stream>>>(xh, xT);
  // P = W1 * G (split; G symmetric so [n][k] tile == G)
  gemm2<128, 64, true, 1, 0><<<dim3(4, 8, NB), blk, 0, stream>>>(
      w1h, w1l, 0, CH, G16h, G16l, CC, CH, P16h, P16l, CC, CH, CH,
      nullptr, nullptr, nullptr, nullptr);
  // scores = P * W2^T + b1 u^T + t b2^T (split)
  gemm2<128, 64, true, 1, 1><<<dim3(4, 8, NB), blk, 0, stream>>>(
      P16h, P16l, CC, CH, w2h, w2l, 0, CH, scores, nullptr, CC, CH, CH, b1, uv, tv, b2);
  softmax_k<<<dim3(CH, NB), blk, 0, stream>>>(scores, b3, attn16, ab3);
  // M = attn * W3
  gemm2<128, 64, false, 1, 2><<<dim3(4, 8, NB), blk, 0, stream>>>(
      attn16, nullptr, CC, CH, w3t, nullptr, 0, CH, M16, nullptr, CC, CH, CH,
      nullptr, nullptr, nullptr, nullptr);
  // den = M x   (f16 write, no RMW)
  gemm2<128, 128, false, 1, 2><<<dim3(4, HW / 128, NB), blk, 0, stream>>>(
      M16, nullptr, CC, CH, xT, nullptr, CHW, CH, den16, nullptr, CHW, HW, CH,
      nullptr, nullptr, nullptr, nullptr);
  // out = x + 0.1*(den + ab3 + local + bg)
  combine_k<<<dim3(CH, NB), blk, 0, stream>>>(x, den16, wg, bg, ab3, out);
}

// Round 7
// 329.877 us; speedup vs baseline: 1.5515x; 1.0216x over previous
//
#include <hip/hip_runtime.h>

typedef _Float16 f16;
typedef _Float16 half8 __attribute__((ext_vector_type(8)));
typedef _Float16 half4 __attribute__((ext_vector_type(4)));
typedef float    f32x4 __attribute__((ext_vector_type(4)));

#define DEV static __device__ __forceinline__

constexpr int NB = 8, CH = 512, HW = 4096, IH = 64, IW = 64;

typedef const __attribute__((address_space(1))) void gas_void;
typedef __attribute__((address_space(3))) void       las_void;

// ---- async staging: f16 global [rows][ld] -> linear LDS [rows][64] ----
template <int ROWS>
DEV void stage_gll(f16* lds, const f16* src, long ld) {
  const int lane = threadIdx.x & 63, w = threadIdx.x >> 6;
  const int r8 = lane >> 3, c16 = lane & 7;
#pragma unroll
  for (int i = w; i < (ROWS / 8); i += 4) {
    const f16* g = src + (long)(i * 8 + r8) * ld + c16 * 8;
    __builtin_amdgcn_global_load_lds((gas_void*)g, (las_void*)(lds + i * 512 + lane * 8), 16, 0, 0);
  }
}

// ---------------- m97-style MFMA GEMM ----------------
// O = A(MxK)*B(KxN); A,B staged [outdim][k] f16 (hi + optional lo split).
// C/D frag mapping: col = lane&15, row = (lane>>4)*4 + j  [verified m89/m91].
// EPI: 0 = split f16 write (O1 hi, O2 lo); 1 = f32 + rank1(e0*e1 + e2*e3);
//      2 = f16; 6 = f32 store into per-ks partial buffer (split-K, no atomics).
template <int BM, int BN, bool SPLIT, int KS, int EPI>
__global__ __launch_bounds__(256, 2) void gemm2(
    const f16* __restrict__ Ah, const f16* __restrict__ Al, long sAb, int lda,
    const f16* __restrict__ Bh, const f16* __restrict__ Bl, long sBb, int ldb,
    void* __restrict__ O1, void* __restrict__ O2, long sOb, int ldo, int K,
    const float* __restrict__ e0, const float* __restrict__ e1,
    const float* __restrict__ e2, const float* __restrict__ e3) {
  constexpr int FM = BM / 32, FN = BN / 32;
  __shared__ f16 sAh[BM * 64], sBh[BN * 64];
  __shared__ f16 sAl[SPLIT ? BM * 64 : 1], sBl[SPLIT ? BN * 64 : 1];

  const int bx = blockIdx.x, by = blockIdx.y;
  const int bz = blockIdx.z, b = bz / KS, ks = bz % KS;
  const int m0 = bx * BM, n0 = by * BN;
  const int lane = threadIdx.x & 63, wave = threadIdx.x >> 6;
  const int wr = (wave >> 1) * (BM / 2), wc = (wave & 1) * (BN / 2);
  const int fr = lane & 15, fq = lane >> 4;

  const f16* Ab  = Ah + b * sAb + (long)m0 * lda;
  const f16* Bb  = Bh + b * sBb + (long)n0 * ldb;
  const f16* Ab2 = SPLIT ? Al + b * sAb + (long)m0 * lda : nullptr;
  const f16* Bb2 = SPLIT ? Bl + b * sBb + (long)n0 * ldb : nullptr;

  f32x4 acc[FM][FN] = {};
  const int kbeg = ks * K, kend = kbeg + K;
  for (int k0 = kbeg; k0 < kend; k0 += 64) {
    stage_gll<BM>(sAh, Ab + k0, lda);
    stage_gll<BN>(sBh, Bb + k0, ldb);
    if constexpr (SPLIT) {
      stage_gll<BM>(sAl, Ab2 + k0, lda);
      stage_gll<BN>(sBl, Bb2 + k0, ldb);
    }
    __syncthreads();
#pragma unroll
    for (int kk = 0; kk < 2; ++kk) {
      half8 ah[FM], bh[FN];
#pragma unroll
      for (int mi = 0; mi < FM; ++mi)
        ah[mi] = *(const half8*)&sAh[(wr + mi * 16 + fr) * 64 + kk * 32 + fq * 8];
#pragma unroll
      for (int ni = 0; ni < FN; ++ni)
        bh[ni] = *(const half8*)&sBh[(wc + ni * 16 + fr) * 64 + kk * 32 + fq * 8];
      if constexpr (SPLIT) {
        half8 al[FM], bl[FN];
#pragma unroll
        for (int mi = 0; mi < FM; ++mi)
          al[mi] = *(const half8*)&sAl[(wr + mi * 16 + fr) * 64 + kk * 32 + fq * 8];
#pragma unroll
        for (int ni = 0; ni < FN; ++ni)
          bl[ni] = *(const half8*)&sBl[(wc + ni * 16 + fr) * 64 + kk * 32 + fq * 8];
#pragma unroll
        for (int mi = 0; mi < FM; ++mi)
#pragma unroll
          for (int ni = 0; ni < FN; ++ni) {
            acc[mi][ni] = __builtin_amdgcn_mfma_f32_16x16x32_f16(ah[mi], bh[ni], acc[mi][ni], 0, 0, 0);
            acc[mi][ni] = __builtin_amdgcn_mfma_f32_16x16x32_f16(ah[mi], bl[ni], acc[mi][ni], 0, 0, 0);
            acc[mi][ni] = __builtin_amdgcn_mfma_f32_16x16x32_f16(al[mi], bh[ni], acc[mi][ni], 0, 0, 0);
          }
      } else {
#pragma unroll
        for (int mi = 0; mi < FM; ++mi)
#pragma unroll
          for (int ni = 0; ni < FN; ++ni)
            acc[mi][ni] = __builtin_amdgcn_mfma_f32_16x16x32_f16(ah[mi], bh[ni], acc[mi][ni], 0, 0, 0);
      }
    }
    __syncthreads();
  }

#pragma unroll
  for (int mi = 0; mi < FM; ++mi)
#pragma unroll
    for (int ni = 0; ni < FN; ++ni)
#pragma unroll
      for (int j = 0; j < 4; ++j) {
        const int row = m0 + wr + mi * 16 + fq * 4 + j;
        const int col = n0 + wc + ni * 16 + fr;
        float g = acc[mi][ni][j];
        const long oi = b * sOb + (long)row * ldo + col;
        if constexpr (EPI == 0) {
          f16 h = (f16)g;
          ((f16*)O1)[oi] = h;
          ((f16*)O2)[oi] = (f16)(g - (float)h);
        } else if constexpr (EPI == 1) {
          g += e0[row] * e1[b * CH + col] + e2[b * CH + row] * e3[col];
          ((float*)O1)[oi] = g;
        } else if constexpr (EPI == 2) {
          ((f16*)O1)[oi] = (f16)g;
        } else {  // EPI == 6: split-K partial, per-ks buffer
          ((float*)O1)[(((long)ks * NB + b) * CH + row) * CH + col] = g;
        }
      }
}

// ---------------- fused den-GEMM + dwconv + residual ----------------
// den = M(CHxCH) * xT(..xC)^T tile (128 chan x 128 pix = 2 image rows);
// out = x + 0.1*(den + ab3[c] + dwconv3x3(xh) + bg[c]).
__global__ __launch_bounds__(256, 2) void gemm_dw(
    const f16* __restrict__ M16, const f16* __restrict__ xT, const f16* __restrict__ xh,
    const float* __restrict__ x, const float* __restrict__ wg, const float* __restrict__ bg,
    const float* __restrict__ ab3, float* __restrict__ out) {
  __shared__ __align__(16) char smem[128 * 4 * 68 * 2];  // 68 KB: stage A+B (32 KB) then xdw
  __shared__ float swg[128][10];
  __shared__ float sbb[128];
  f16* sA  = (f16*)smem;
  f16* sB  = (f16*)(smem + 128 * 64 * 2);
  f16* xdw = (f16*)smem;

  const int b = blockIdx.z;
  const int c0 = blockIdx.x * 128, p0 = blockIdx.y * 128;
  const int h0 = p0 >> 6;  // first of the 2 image rows this tile covers
  const int lane = threadIdx.x & 63, wave = threadIdx.x >> 6;
  const int wr = (wave >> 1) * 64, wc = (wave & 1) * 64;
  const int fr = lane & 15, fq = lane >> 4;
  const long CC = (long)CH * CH, CHW = (long)CH * HW;

  // prologue: weights + fused bias into LDS (consumed after K-loop)
  for (int q = threadIdx.x; q < 128 * 9; q += 256)
    swg[q / 9][q % 9] = wg[(c0 + q / 9) * 9 + q % 9];
  for (int c = threadIdx.x; c < 128; c += 256)
    sbb[c] = bg[c0 + c] + ab3[b * CH + c0 + c];

  const f16* Ab = M16 + b * CC + (long)c0 * CH;
  const f16* Bb = xT + b * CHW + (long)p0 * CH;

  f32x4 acc[4][4] = {};
  for (int k0 = 0; k0 < CH; k0 += 64) {
    stage_gll<128>(sA, Ab + k0, CH);
    stage_gll<128>(sB, Bb + k0, CH);
    __syncthreads();
#pragma unroll
    for (int kk = 0; kk < 2; ++kk) {
      half8 ah[4], bh[4];
#pragma unroll
      for (int mi = 0; mi < 4; ++mi)
        ah[mi] = *(const half8*)&sA[(wr + mi * 16 + fr) * 64 + kk * 32 + fq * 8];
#pragma unroll
      for (int ni = 0; ni < 4; ++ni)
        bh[ni] = *(const half8*)&sB[(wc + ni * 16 + fr) * 64 + kk * 32 + fq * 8];
#pragma unroll
      for (int mi = 0; mi < 4; ++mi)
#pragma unroll
        for (int ni = 0; ni < 4; ++ni)
          acc[mi][ni] = __builtin_amdgcn_mfma_f32_16x16x32_f16(ah[mi], bh[ni], acc[mi][ni], 0, 0, 0);
    }
    __syncthreads();
  }

  // stage dwconv tile: xdw[c][dy][68], image rows h0-1..h0+2, cols 0..63 (rest pad)
  for (int q = threadIdx.x; q < 128 * 4 * 16; q += 256) {
    const int c = q >> 6, dy = (q >> 4) & 3, w4 = (q & 15) * 4;
    const int hg = h0 - 1 + dy;
    half4 v = {};
    if (hg >= 0 && hg < IH)
      v = *(const half4*)(xh + ((long)b * CH + c0 + c) * HW + hg * 64 + w4);
    *(half4*)&xdw[(c * 4 + dy) * 68 + w4] = v;
  }
  __syncthreads();

#pragma unroll
  for (int mi = 0; mi < 4; ++mi)
#pragma unroll
    for (int j = 0; j < 4; ++j) {
      const int ci = wr + mi * 16 + fq * 4 + j;
      float wgt[9];
#pragma unroll
      for (int k = 0; k < 9; ++k) wgt[k] = swg[ci][k];
      const float bb = sbb[ci];
      const long rowbase = ((long)b * CH + c0 + ci) * HW + p0;
#pragma unroll
      for (int ni = 0; ni < 4; ++ni) {
        const int px = wc + ni * 16 + fr;
        const int h = px >> 6, w = px & 63;
        float dw = 0.f;
#pragma unroll
        for (int dy = 0; dy < 3; ++dy)
#pragma unroll
          for (int dx = 0; dx < 3; ++dx) {
            const int wx = w + dx - 1;
            const float tap =
                (wx >= 0 && wx < IW) ? (float)xdw[(ci * 4 + h + dy) * 68 + wx] : 0.f;
            dw += wgt[dy * 3 + dx] * tap;
          }
        const float xv = x[rowbase + px];
        out[rowbase + px] = xv + 0.1f * (acc[mi][ni][j] + bb + dw);
      }
    }
}

// ---------------- reductions ----------------
template <int OP>  // 0 = sum, 1 = max
DEV float blockReduce(float v) {
#pragma unroll
  for (int o = 32; o; o >>= 1) {
    float w = __shfl_xor(v, o);
    v = OP ? fmaxf(v, w) : v + w;
  }
  __shared__ float t[4];
  __shared__ float res;
  __syncthreads();
  if ((threadIdx.x & 63) == 0) t[threadIdx.x >> 6] = v;
  __syncthreads();
  if (threadIdx.x == 0)
    res = OP ? fmaxf(fmaxf(t[0], t[1]), fmaxf(t[2], t[3])) : t[0] + t[1] + t[2] + t[3];
  __syncthreads();
  return res;
}

// ---------------- prep / small kernels ----------------
// x (f32 row) -> xh = f16(x), xm = f16(2x - xh)  + exact full-row sum -> sv
__global__ __launch_bounds__(256) void convert1(const float* __restrict__ x, f16* __restrict__ xh,
                                                f16* __restrict__ xm, float* __restrict__ sv) {
  const int c = blockIdx.x, b = blockIdx.y;
  const long base = ((long)(b * CH + c)) * HW;
  const float* p = x + base;
  f16* ph = xh + base;
  f16* pm = xm + base;
  float s = 0.f;
#pragma unroll
  for (int i0 = 0; i0 < 4; ++i0) {
    const int i = (threadIdx.x + i0 * 256) * 4;
    f32x4 v = *(const f32x4*)(p + i);
    half4 h, m;
#pragma unroll
    for (int j = 0; j < 4; ++j) {
      f16 hi = (f16)v[j];
      h[j] = hi;
      m[j] = (f16)(2.f * v[j] - (float)hi);
      s += v[j];
    }
    *(half4*)(ph + i) = h;
    *(half4*)(pm + i) = m;
  }
  s = blockReduce<0>(s);
  if (threadIdx.x == 0) sv[b * CH + c] = s;
}

// xh [B][C][HW] -> xT [B][HW][C]  (f16 transpose via LDS)
__global__ __launch_bounds__(256) void convert2(const f16* __restrict__ xh, f16* __restrict__ xT) {
  const int p0 = blockIdx.x * 64, c0 = blockIdx.y * 64, b = blockIdx.z;
  __shared__ f16 tl[64][72];
  const int t = threadIdx.x;
  const int cr = t >> 2, pc = (t & 3) * 16;
  const f16* src = xh + ((long)(b * CH) + c0 + cr) * HW + p0 + pc;
  half8 a0 = *(const half8*)src, a1 = *(const half8*)(src + 8);
#pragma unroll
  for (int j = 0; j < 8; ++j) {
    tl[pc + j][cr] = a0[j];
    tl[pc + 8 + j][cr] = a1[j];
  }
  __syncthreads();
  f16* dst = xT + ((long)b * HW + p0 + cr) * CH + c0 + pc;
  *(half8*)dst       = *(half8*)&tl[cr][pc];
  *(half8*)(dst + 8) = *(half8*)&tl[cr][pc + 8];
}

// G = (E + E^T)/2 summed over KS partials -> hi/lo f16
template <int KS>
__global__ __launch_bounds__(256) void cvt_g(const float* __restrict__ E, f16* __restrict__ Gh,
                                             f16* __restrict__ Gl) {
  const int c0 = blockIdx.x * 64, r0 = blockIdx.y * 64, b = blockIdx.z;
  __shared__ float tl[64][65];
  const int t = threadIdx.x;
  const int rr0 = t >> 4, c4 = (t & 15) * 4;
  f32x4 acc[4] = {};
  for (int ks = 0; ks < KS; ++ks) {
    const float* Eb = E + ((long)ks * NB + b) * (long)CH * CH;
#pragma unroll
    for (int i = 0; i < 4; ++i)
      acc[i] += *(const f32x4*)(Eb + (long)(r0 + rr0 + i * 16) * CH + c0 + c4);
    __syncthreads();
#pragma unroll
    for (int i = 0; i < 4; ++i) {
      f32x4 w = *(const f32x4*)(Eb + (long)(c0 + rr0 + i * 16) * CH + r0 + c4);
#pragma unroll
      for (int j = 0; j < 4; ++j) tl[rr0 + i * 16][c4 + j] = w[j];
    }
    __syncthreads();
#pragma unroll
    for (int i = 0; i < 4; ++i)
#pragma unroll
      for (int j = 0; j < 4; ++j) acc[i][j] += tl[c4 + j][rr0 + i * 16];
  }
#pragma unroll
  for (int i = 0; i < 4; ++i) {
    half4 h, l;
#pragma unroll
    for (int j = 0; j < 4; ++j) {
      const float g = 0.5f * acc[i][j];
      f16 hi = (f16)g;
      h[j] = hi;
      l[j] = (f16)(g - (float)hi);
    }
    const long oi = ((long)b * CH + r0 + rr0 + i * 16) * CH + c0 + c4;
    *(half4*)(Gh + oi) = h;
    *(half4*)(Gl + oi) = l;
  }
}

__global__ __launch_bounds__(256) void prep_w(const float* __restrict__ w1, const float* __restrict__ w2,
                                              const float* __restrict__ w3, f16* w1h, f16* w1l, f16* w2h,
                                              f16* w2l, f16* w3t) {
  const int i = blockIdx.x * 256 + threadIdx.x;
  if (i >= CH * CH) return;
  float a = w1[i];
  f16 h = (f16)a;
  w1h[i] = h;
  w1l[i] = (f16)(a - (float)h);
  float bv = w2[i];
  h = (f16)bv;
  w2h[i] = h;
  w2l[i] = (f16)(bv - (float)h);
  const int r = i >> 9, c = i & 511;
  w3t[c * CH + r] = (f16)w3[i];
}

__global__ __launch_bounds__(256) void prep_tu(const float* __restrict__ w1, const float* __restrict__ w2,
                                               const float* __restrict__ b2, const float* __restrict__ s,
                                               float* __restrict__ t, float* __restrict__ u) {
  const int b = blockIdx.y, c = blockIdx.x;
  float a1 = 0.f, a2 = 0.f;
  for (int i = threadIdx.x; i < CH; i += 256) {
    float sv = s[b * CH + i];
    a1 += w1[(long)c * CH + i] * sv;
    a2 += w2[(long)c * CH + i] * sv;
  }
  a1 = blockReduce<0>(a1);
  a2 = blockReduce<0>(a2);
  if (threadIdx.x == 0) {
    t[b * CH + c] = a1;
    u[b * CH + c] = a2 + (float)HW * b2[c];
  }
}

__global__ __launch_bounds__(256) void softmax_k(const float* __restrict__ sc, const float* __restrict__ b3,
                                                 f16* __restrict__ attn, float* __restrict__ ab3) {
  const int b = blockIdx.y, c = blockIdx.x;
  const float* row = sc + ((long)(b * CH + c)) * CH;
  const float v0 = row[threadIdx.x], v1 = row[threadIdx.x + 256];
  const float m = blockReduce<1>(fmaxf(v0, v1));
  const float q0 = __expf(v0 - m), q1 = __expf(v1 - m);
  const float sum = blockReduce<0>(q0 + q1);
  const float sb = blockReduce<0>(q0 * b3[threadIdx.x] + q1 * b3[threadIdx.x + 256]);
  const float inv = 1.f / sum;
  attn[((long)(b * CH + c)) * CH + threadIdx.x] = (f16)(q0 * inv);
  attn[((long)(b * CH + c)) * CH + threadIdx.x + 256] = (f16)(q1 * inv);
  if (threadIdx.x == 0) ab3[b * CH + c] = sb * inv;
}

// ---------------- launch ----------------
extern "C" void kernel_launch(void* const* d_in, const int* in_sizes, int n_in, void* d_out, int out_size,
                              void* d_ws, size_t ws_size, hipStream_t stream) {
  const float* x  = (const float*)d_in[0];
  const float* w1 = (const float*)d_in[1];
  const float* b1 = (const float*)d_in[2];
  const float* w2 = (const float*)d_in[3];
  const float* b2 = (const float*)d_in[4];
  const float* w3 = (const float*)d_in[5];
  const float* b3 = (const float*)d_in[6];
  const float* wg = (const float*)d_in[7];
  const float* bg = (const float*)d_in[8];
  float* out = (float*)d_out;

  char* ws = (char*)d_ws;
  size_t off = 0;
  auto alloc = [&](size_t bytes) -> void* {
    void* p = ws + off;
    off += (bytes + 255) & ~(size_t)255;
    return p;
  };
  const long CC = (long)CH * CH;
  const long CHW = (long)CH * HW;
  constexpr int GKS = 4;  // Gram split-K factor
  f16* xh    = (f16*)alloc(NB * CHW * 2);
  f16* xm    = (f16*)alloc(NB * CHW * 2);
  float* Epart = (float*)alloc((long)GKS * NB * CC * 4);
  f16* G16h = (f16*)alloc(NB * CC * 2);
  f16* G16l = (f16*)alloc(NB * CC * 2);
  f16* P16h = (f16*)alloc(NB * CC * 2);
  f16* P16l = (f16*)alloc(NB * CC * 2);
  f16* w1h = (f16*)alloc(CC * 2);
  f16* w1l = (f16*)alloc(CC * 2);
  f16* w2h = (f16*)alloc(CC * 2);
  f16* w2l = (f16*)alloc(CC * 2);
  f16* w3t = (f16*)alloc(CC * 2);
  float* sv = (float*)alloc(NB * CH * 4);
  float* tv = (float*)alloc(NB * CH * 4);
  float* uv = (float*)alloc(NB * CH * 4);
  float* ab3 = (float*)alloc(NB * CH * 4);
  // disjoint-liveness aliases (strictly stream-ordered producer -> consumer):
  f16* xT = (f16*)Epart;                               // Epart dead after cvt_g
  float* scores = (float*)xm;                          // xm dead after Gram (8 MB of 32)
  f16* attn16 = (f16*)((char*)xm + (NB * CC * 4));     // +8 MB, 4 MB
  f16* M16    = (f16*)((char*)xm + (NB * CC * 4) + (NB * CC * 2));  // +12 MB, 4 MB
  // NOTE: xh stays live to the end (gemm_dw dwconv taps).

  const dim3 blk(256);

  prep_w<<<dim3((CH * CH + 255) / 256), blk, 0, stream>>>(w1, w2, w3, w1h, w1l, w2h, w2l, w3t);
  convert1<<<dim3(CH, NB), blk, 0, stream>>>(x, xh, xm, sv);
  prep_tu<<<dim3(CH, NB), blk, 0, stream>>>(w1, w2, b2, sv, tv, uv);

  // E = xh * xm^T, all 16 tile-pairs, split-K4 into per-ks partial buffers
  gemm2<128, 128, false, GKS, 6><<<dim3(4, 4, NB * GKS), blk, 0, stream>>>(
      xh, nullptr, CHW, HW, xm, nullptr, CHW, HW, Epart, nullptr, CC, CH, HW / GKS,
      nullptr, nullptr, nullptr, nullptr);
  // G = (E + E^T)/2, fold KS partials, hi/lo split
  cvt_g<GKS><<<dim3(8, 8, NB), blk, 0, stream>>>(Epart, G16h, G16l);
  // xT = transpose(xh)  (into dead Epart slot)
  convert2<<<dim3(HW / 64, CH / 64, NB), blk, 0, stream>>>(xh, xT);
  // P = W1 * G (split; G symmetric so [n][k] tile == G)
  gemm2<128, 64, true, 1, 0><<<dim3(4, 8, NB), blk, 0, stream>>>(
      w1h, w1l, 0, CH, G16h, G16l, CC, CH, P16h, P16l, CC, CH, CH,
      nullptr, nullptr, nullptr, nullptr);
  // scores = P * W2^T + b1 u^T + t b2^T (split)
  gemm2<128, 64, true, 1, 1><<<dim3(4, 8, NB), blk, 0, stream>>>(
      P16h, P16l, CC, CH, w2h, w2l, 0, CH, scores, nullptr, CC, CH, CH, b1, uv, tv, b2);
  softmax_k<<<dim3(CH, NB), blk, 0, stream>>>(scores, b3, attn16, ab3);
  // M = attn * W3
  gemm2<128, 64, false, 1, 2><<<dim3(4, 8, NB), blk, 0, stream>>>(
      attn16, nullptr, CC, CH, w3t, nullptr, 0, CH, M16, nullptr, CC, CH, CH,
      nullptr, nullptr, nullptr, nullptr);
  // out = x + 0.1*(M x + ab3 + dwconv(xh) + bg)  — fused epilogue, no den16
  gemm_dw<<<dim3(CH / 128, HW / 128, NB), blk, 0, stream>>>(
      M16, xT, xh, x, wg, bg, ab3, out);
}